// Round 9
// baseline (3081.120 us; speedup 1.0000x reference)
//
#include <hip/hip_runtime.h>
#include <hip/hip_bf16.h>
#include <stdint.h>

#define B_ 8
#define L_ 512
#define H_ 768
#define WW_ 12
#define C_ 25
#define S_ (L_*WW_)   // 6144
#define HH 384        // H/2
#define G4 1536       // 4*HH

using bf16x8 = __attribute__((ext_vector_type(8))) short;
using f32x4  = __attribute__((ext_vector_type(4))) float;

static __device__ __forceinline__ unsigned short f2bf(float x){
  unsigned u = __float_as_uint(x);
  unsigned r = (u + 0x7FFFu + ((u >> 16) & 1u)) >> 16;
  return (unsigned short)r;
}
static __device__ __forceinline__ float bflo(unsigned u){ return __uint_as_float(u << 16); }
static __device__ __forceinline__ float bfhi(unsigned u){ return __uint_as_float(u & 0xFFFF0000u); }

static __device__ __forceinline__ float sigmoid_f(float x){
  x = fminf(15.f, fmaxf(-15.f, x));
  return 1.f / (1.f + __expf(-x));
}
static __device__ __forceinline__ float tanh_f(float x){
  x = fminf(15.f, fmaxf(-15.f, x));
  float e = __expf(-2.f * x);
  return (1.f - e) / (1.f + e);
}

// global -> LDS direct DMA, 16 B per lane (dest = wave-uniform base + lane*16)
static __device__ __forceinline__ void gl_lds16(const unsigned short* g, unsigned short* l){
  __builtin_amdgcn_global_load_lds(
      (const __attribute__((address_space(1))) unsigned int*)g,
      (__attribute__((address_space(3))) unsigned int*)l,
      16, 0, 0);
}

// ---------------- fp32 -> bf16 cast (n multiple of 4) ----------------
__global__ void k_cast_bf16(const float* __restrict__ s, unsigned short* __restrict__ d, long n4){
  long i = (long)blockIdx.x * blockDim.x + threadIdx.x;
  if (i >= n4) return;
  float4 v = reinterpret_cast<const float4*>(s)[i];
  ushort4 o;
  o.x = f2bf(v.x); o.y = f2bf(v.y); o.z = f2bf(v.z); o.w = f2bf(v.w);
  reinterpret_cast<ushort4*>(d)[i] = o;
}

__global__ void k_biascomb(const float* __restrict__ a, const float* __restrict__ b,
                           float* __restrict__ o, int n){
  int i = blockIdx.x * blockDim.x + threadIdx.x;
  if (i < n) o[i] = a[i] + b[i];
}

// ---------------- LDS-staged NT GEMM (m97 structure) ----------------
template<int ACT, int OUTBF>
__global__ __launch_bounds__(256) void k_gemm2(
    const unsigned short* __restrict__ A, const unsigned short* __restrict__ Bm,
    const float* __restrict__ bias, void* __restrict__ Cout,
    int M, int N, int K, int ldb)
{
  __shared__ unsigned short Al[128 * 64];
  __shared__ unsigned short Bl[128 * 64];

  const int tid  = threadIdx.x;
  const int lane = tid & 63;
  const int wave = tid >> 6;
  const int wr = wave >> 1, wc = wave & 1;
  const int l16 = lane & 15, lq = lane >> 4;
  const int m0 = blockIdx.y * 128;
  const int n0 = blockIdx.x * 128;

  const int r_ = tid >> 3;
  const int p_ = tid & 7;
  const int cS = ((p_ ^ (r_ & 7)) * 8);
  const unsigned short* Asrc[4];
  const unsigned short* Bsrc[4];
  #pragma unroll
  for (int i = 0; i < 4; i++){
    int ra = m0 + i * 32 + r_; ra = ra < M ? ra : (M - 1);
    Asrc[i] = A + (size_t)ra * K + cS;
    int rb = n0 + i * 32 + r_; rb = rb < N ? rb : (N - 1);
    Bsrc[i] = Bm + (size_t)rb * ldb + cS;
  }

  f32x4 acc[4][4];
  #pragma unroll
  for (int a = 0; a < 4; a++)
    #pragma unroll
    for (int b = 0; b < 4; b++)
      acc[a][b] = (f32x4)0.f;

  const int sw0 = ((0 * 4 + lq) ^ (l16 & 7)) * 16;
  const int sw1 = ((1 * 4 + lq) ^ (l16 & 7)) * 16;
  const int aBase = (wr * 64 + l16) * 128;
  const int bBase = (wc * 64 + l16) * 128;

  for (int k0 = 0; k0 < K; k0 += 64){
    #pragma unroll
    for (int i = 0; i < 4; i++)
      gl_lds16(Asrc[i] + k0, Al + i * 2048 + tid * 8);
    #pragma unroll
    for (int i = 0; i < 4; i++)
      gl_lds16(Bsrc[i] + k0, Bl + i * 2048 + tid * 8);
    __syncthreads();

    #pragma unroll
    for (int kk = 0; kk < 2; kk++){
      const int sw = kk ? sw1 : sw0;
      bf16x8 av[4], bv[4];
      #pragma unroll
      for (int mi = 0; mi < 4; mi++)
        av[mi] = *reinterpret_cast<const bf16x8*>((const char*)Al + aBase + mi * 2048 + sw);
      #pragma unroll
      for (int ni = 0; ni < 4; ni++)
        bv[ni] = *reinterpret_cast<const bf16x8*>((const char*)Bl + bBase + ni * 2048 + sw);
      #pragma unroll
      for (int mi = 0; mi < 4; mi++)
        #pragma unroll
        for (int ni = 0; ni < 4; ni++)
          acc[mi][ni] = __builtin_amdgcn_mfma_f32_16x16x32_bf16(av[mi], bv[ni], acc[mi][ni], 0, 0, 0);
    }
    __syncthreads();
  }

  #pragma unroll
  for (int mi = 0; mi < 4; mi++){
    #pragma unroll
    for (int r = 0; r < 4; r++){
      int row = m0 + wr * 64 + mi * 16 + lq * 4 + r;
      if (row >= M) continue;
      #pragma unroll
      for (int ni = 0; ni < 4; ni++){
        int col = n0 + wc * 64 + ni * 16 + l16;
        float v = acc[mi][ni][r] + bias[col];
        if (ACT) v = v > 0.f ? v : 0.f;
        if (OUTBF) ((unsigned short*)Cout)[(size_t)row * N + col] = f2bf(v);
        else       ((float*)Cout)[(size_t)row * N + col] = v;
      }
    }
  }
}

// ---------------- fused out-projection GEMM --------------------------------
__global__ __launch_bounds__(256) void k_gout(
    const unsigned short* __restrict__ Ps, const unsigned short* __restrict__ Pe,
    const int* __restrict__ sidx, const float* __restrict__ b1,
    const unsigned short* __restrict__ Bw, const float* __restrict__ b2,
    float* __restrict__ out)
{
  __shared__ unsigned short Al[128 * 64];
  __shared__ unsigned short Bl[128 * 64];
  __shared__ int idx2[128][2];

  const int tid  = threadIdx.x;
  const int lane = tid & 63;
  const int wave = tid >> 6;
  const int wr = wave >> 1, wc = wave & 1;
  const int l16 = lane & 15, lq = lane >> 4;
  const int tm = blockIdx.y;            // 0..383
  const int b  = tm / 48;
  const int s0 = (tm % 48) * 128;
  const int n0 = blockIdx.x * 128;      // 0..5 -> 768

  if (tid < 128){
    int s = s0 + tid;
    int i0 = sidx[((size_t)b * S_ + s) * 2 + 0];
    int i1 = sidx[((size_t)b * S_ + s) * 2 + 1];
    idx2[tid][0] = min(max(i0, 0), L_ - 1);
    idx2[tid][1] = min(max(i1, 0), L_ - 1);
  }
  __syncthreads();

  const int r_ = tid >> 3;
  const int p_ = tid & 7;
  const int cS = ((p_ ^ (r_ & 7)) * 8);
  const unsigned short* Bsrc[4];
  const unsigned short* As0[4];
  const unsigned short* As1[4];
  #pragma unroll
  for (int i = 0; i < 4; i++){
    Bsrc[i] = Bw + (size_t)(n0 + i * 32 + r_) * 3072 + cS;
    int rr = i * 32 + r_;
    As0[i] = Ps + (size_t)(b * L_ + idx2[rr][0]) * 3072 + cS;
    As1[i] = Pe + (size_t)(b * L_ + idx2[rr][1]) * 3072 + cS;
  }

  f32x4 acc[4][4];
  #pragma unroll
  for (int a = 0; a < 4; a++)
    #pragma unroll
    for (int c = 0; c < 4; c++)
      acc[a][c] = (f32x4)0.f;

  const int sw0 = ((0 * 4 + lq) ^ (l16 & 7)) * 16;
  const int sw1 = ((1 * 4 + lq) ^ (l16 & 7)) * 16;
  const int aBase = (wr * 64 + l16) * 128;
  const int bBase = (wc * 64 + l16) * 128;

  for (int k0 = 0; k0 < 3072; k0 += 64){
    #pragma unroll
    for (int i = 0; i < 4; i++)
      gl_lds16(Bsrc[i] + k0, Bl + i * 2048 + tid * 8);
    float4 bb0 = *reinterpret_cast<const float4*>(b1 + k0 + cS);
    float4 bb1 = *reinterpret_cast<const float4*>(b1 + k0 + cS + 4);
    #pragma unroll
    for (int i = 0; i < 4; i++){
      uint4 va = *reinterpret_cast<const uint4*>(As0[i] + k0);
      uint4 ve = *reinterpret_cast<const uint4*>(As1[i] + k0);
      float f[8];
      f[0] = bflo(va.x) + bflo(ve.x) + bb0.x; f[1] = bfhi(va.x) + bfhi(ve.x) + bb0.y;
      f[2] = bflo(va.y) + bflo(ve.y) + bb0.z; f[3] = bfhi(va.y) + bfhi(ve.y) + bb0.w;
      f[4] = bflo(va.z) + bflo(ve.z) + bb1.x; f[5] = bfhi(va.z) + bfhi(ve.z) + bb1.y;
      f[6] = bflo(va.w) + bflo(ve.w) + bb1.z; f[7] = bfhi(va.w) + bfhi(ve.w) + bb1.w;
      unsigned short e[8];
      #pragma unroll
      for (int j = 0; j < 8; j++){ float v = f[j] > 0.f ? f[j] : 0.f; e[j] = f2bf(v); }
      uint4 rr;
      rr.x = (unsigned)e[0] | ((unsigned)e[1] << 16);
      rr.y = (unsigned)e[2] | ((unsigned)e[3] << 16);
      rr.z = (unsigned)e[4] | ((unsigned)e[5] << 16);
      rr.w = (unsigned)e[6] | ((unsigned)e[7] << 16);
      *reinterpret_cast<uint4*>(Al + i * 2048 + tid * 8) = rr;
    }
    __syncthreads();

    #pragma unroll
    for (int kk = 0; kk < 2; kk++){
      const int sw = kk ? sw1 : sw0;
      bf16x8 av[4], bv[4];
      #pragma unroll
      for (int mi = 0; mi < 4; mi++)
        av[mi] = *reinterpret_cast<const bf16x8*>((const char*)Al + aBase + mi * 2048 + sw);
      #pragma unroll
      for (int ni = 0; ni < 4; ni++)
        bv[ni] = *reinterpret_cast<const bf16x8*>((const char*)Bl + bBase + ni * 2048 + sw);
      #pragma unroll
      for (int mi = 0; mi < 4; mi++)
        #pragma unroll
        for (int ni = 0; ni < 4; ni++)
          acc[mi][ni] = __builtin_amdgcn_mfma_f32_16x16x32_bf16(av[mi], bv[ni], acc[mi][ni], 0, 0, 0);
    }
    __syncthreads();
  }

  #pragma unroll
  for (int mi = 0; mi < 4; mi++){
    #pragma unroll
    for (int r = 0; r < 4; r++){
      size_t row = (size_t)tm * 128 + wr * 64 + mi * 16 + lq * 4 + r;
      #pragma unroll
      for (int ni = 0; ni < 4; ni++){
        int col = n0 + wc * 64 + ni * 16 + l16;
        out[row * 768 + col] = acc[mi][ni][r] + b2[col];
      }
    }
  }
}

// ---------------- distributed LSTM v8 ---------------------------------------
// k_lstm7 (978us) + FIFO hygiene: (a) xg prefetch issued AFTER the poll spin
// (hidden under MFMA/combine/next-spin instead of draining inside the poll
// wait), (b) hbf output stores register-buffered and flushed every 8 steps
// (store acks leave the per-step vmcnt path), (c) mask group-loaded.
// Only per-step store left in the FIFO is the hg tag word (critical path).
static __device__ __forceinline__ unsigned long long ald8(const unsigned long long* p){
  return __hip_atomic_load(p, __ATOMIC_RELAXED, __HIP_MEMORY_SCOPE_AGENT);
}

__global__ __launch_bounds__(512, 2) void k_lstm8(
    const float* __restrict__ xgf, const float* __restrict__ xgb,
    const unsigned short* __restrict__ Wbf,   // [2][1536][384] bf16
    const int* __restrict__ mask,
    unsigned short* __restrict__ hbf,         // [4096][768] bf16 out (masked)
    unsigned int* __restrict__ hg)            // [2][2][3072] tagged words (pre-zeroed)
{
  const int dir  = blockIdx.x / 6;
  const int part = blockIdx.x % 6;
  const int tid  = threadIdx.x;
  const int lane = tid & 63;
  const int w    = tid >> 6;            // wave 0..7
  const int l16  = lane & 15, lq = lane >> 4;

  __shared__ alignas(16) unsigned short hls[8 * HH];   // 6 KB, XOR-swizzled
  __shared__ float gsl[256 * 9];                        // padded gate staging

  const float* xg = dir ? xgb : xgf;
  const unsigned short* Wg = Wbf + (size_t)dir * G4 * HH;
  unsigned int* hgd = hg + dir * 2 * (8 * HH);

  // resident W_hh B-frags: wave w covers local gate-rows w*32 .. w*32+31
  bf16x8 bfr0[12], bfr1[12];
  {
    int r0 = w * 32 + l16;
    int r1 = w * 32 + 16 + l16;
    int g0 = r0 >> 6, j0u = r0 & 63;
    int g1 = r1 >> 6, j1u = r1 & 63;
    const unsigned short* p0 = Wg + ((size_t)g0 * HH + part * 64 + j0u) * HH + lq * 8;
    const unsigned short* p1 = Wg + ((size_t)g1 * HH + part * 64 + j1u) * HH + lq * 8;
    #pragma unroll
    for (int kf = 0; kf < 12; kf++){
      bfr0[kf] = *reinterpret_cast<const bf16x8*>(p0 + kf * 32);
      bfr1[kf] = *reinterpret_cast<const bf16x8*>(p1 + kf * 32);
    }
  }

  if (tid < 384) reinterpret_cast<uint4*>(hls)[tid] = uint4{0,0,0,0};

  const int cb = tid >> 6;          // combine: batch = wave
  const int cj = tid & 63;          // combine: unit within part
  const int cu = part * 64 + cj;    // global unit
  float c_state = 0.f;

  const int w0  = tid * 6;
  const int rb  = w0 / HH;
  const int ru  = w0 % HH;

  // step-0 xg
  float xi, xf, xgg, xo;
  {
    const int t0 = dir ? (L_ - 1) : 0;
    const float* xr = xg + ((size_t)cb * L_ + t0) * G4;
    xi = xr[cu]; xf = xr[HH + cu]; xgg = xr[2 * HH + cu]; xo = xr[3 * HH + cu];
  }

  __syncthreads();

  for (int s8 = 0; s8 < L_; s8 += 8){
    // group-load 8 mask values (L2-warm after first group)
    float mv[8];
    #pragma unroll
    for (int k = 0; k < 8; k++){
      int tk = dir ? (L_ - 1 - (s8 + k)) : (s8 + k);
      mv[k] = (float)mask[cb * L_ + tk];
    }
    unsigned short hob[8];

    #pragma unroll
    for (int k = 0; k < 8; k++){
      const int s = s8 + k;
      const int t = dir ? (L_ - 1 - s) : s;

      // ---- 1) poll h(s-1): issue + combined-retry spin + LDS scatter ----
      if (s > 0){
        const unsigned long long tg = (unsigned long long)s;
        const unsigned long long* P =
          reinterpret_cast<const unsigned long long*>(hgd + ((s - 1) & 1) * (8 * HH) + w0);
        unsigned long long v0 = ald8(P), v1 = ald8(P + 1), v2 = ald8(P + 2);
        for (;;){
          bool ok0 = (((v0 >> 16) & 0xFFFFull) == tg) & ((v0 >> 48) == tg);
          bool ok1 = (((v1 >> 16) & 0xFFFFull) == tg) & ((v1 >> 48) == tg);
          bool ok2 = (((v2 >> 16) & 0xFFFFull) == tg) & ((v2 >> 48) == tg);
          if (ok0 & ok1 & ok2) break;
          v0 = ald8(P); v1 = ald8(P + 1); v2 = ald8(P + 2);
        }
        unsigned p01 = (unsigned)(v0 & 0xFFFFu) | ((unsigned)((v0 >> 32) & 0xFFFFu) << 16);
        unsigned p23 = (unsigned)(v1 & 0xFFFFu) | ((unsigned)((v1 >> 32) & 0xFFFFu) << 16);
        unsigned p45 = (unsigned)(v2 & 0xFFFFu) | ((unsigned)((v2 >> 32) & 0xFFFFu) << 16);
        *reinterpret_cast<unsigned*>((char*)hls + ((rb * 768 + (ru    ) * 2) ^ (rb << 4))) = p01;
        *reinterpret_cast<unsigned*>((char*)hls + ((rb * 768 + (ru + 2) * 2) ^ (rb << 4))) = p23;
        *reinterpret_cast<unsigned*>((char*)hls + ((rb * 768 + (ru + 4) * 2) ^ (rb << 4))) = p45;
      }
      __syncthreads();

      // ---- 2) issue next-step xg prefetch (AFTER spin: never in poll FIFO;
      //         consumed next iteration -> latency hidden under MFMA+combine+spin)
      float nxi = 0.f, nxf = 0.f, nxg = 0.f, nxo = 0.f;
      if (s + 1 < L_){
        const int tn = dir ? (L_ - 2 - s) : (s + 1);
        const float* xr = xg + ((size_t)cb * L_ + tn) * G4;
        nxi = xr[cu]; nxf = xr[HH + cu]; nxg = xr[2 * HH + cu]; nxo = xr[3 * HH + cu];
      }

      // ---- 3) gates = h @ Wslice^T ----
      f32x4 acc0 = (f32x4)0.f, acc1 = (f32x4)0.f;
      const int arow = l16 & 7;
      #pragma unroll
      for (int kf = 0; kf < 12; kf++){
        int by = (arow * 768 + kf * 64 + lq * 16) ^ (arow << 4);
        bf16x8 a = *reinterpret_cast<const bf16x8*>((const char*)hls + by);
        acc0 = __builtin_amdgcn_mfma_f32_16x16x32_bf16(a, bfr0[kf], acc0, 0, 0, 0);
        acc1 = __builtin_amdgcn_mfma_f32_16x16x32_bf16(a, bfr1[kf], acc1, 0, 0, 0);
      }
      if (lq < 2){
        int n0r = w * 32 + l16;
        int n1r = w * 32 + 16 + l16;
        #pragma unroll
        for (int r = 0; r < 4; r++){
          gsl[n0r * 9 + lq * 4 + r] = acc0[r];
          gsl[n1r * 9 + lq * 4 + r] = acc1[r];
        }
      }
      __syncthreads();

      // ---- 4) combine + critical hg store; hbf buffered ----
      {
        float gi = gsl[(0 * 64 + cj) * 9 + cb] + xi;
        float gf = gsl[(1 * 64 + cj) * 9 + cb] + xf;
        float gg = gsl[(2 * 64 + cj) * 9 + cb] + xgg;
        float go = gsl[(3 * 64 + cj) * 9 + cb] + xo;
        c_state = sigmoid_f(gf) * c_state + sigmoid_f(gi) * tanh_f(gg);
        float h = sigmoid_f(go) * tanh_f(c_state);
        unsigned short hb = f2bf(h);
        *reinterpret_cast<unsigned short*>((char*)hls + ((cb * 768 + cu * 2) ^ (cb << 4))) = hb;
        unsigned word = ((unsigned)(s + 1) << 16) | (unsigned)hb;
        __hip_atomic_store(&hgd[(s & 1) * (8 * HH) + cb * HH + cu], word,
                           __ATOMIC_RELAXED, __HIP_MEMORY_SCOPE_AGENT);
        hob[k] = f2bf(h * mv[k]);
      }

      xi = nxi; xf = nxf; xgg = nxg; xo = nxo;
    }

    // ---- flush 8 buffered hbf rows (acks overlap the next group's steps) ----
    #pragma unroll
    for (int k = 0; k < 8; k++){
      int tk = dir ? (L_ - 1 - (s8 + k)) : (s8 + k);
      hbf[((size_t)cb * L_ + tk) * H_ + dir * HH + cu] = hob[k];
    }
  }
}

extern "C" void kernel_launch(void* const* d_in, const int* in_sizes, int n_in,
                              void* d_out, int out_size, void* d_ws, size_t ws_size,
                              hipStream_t stream)
{
  (void)in_sizes; (void)n_in; (void)out_size; (void)ws_size;
  const float* we     = (const float*)d_in[0];
  const int*   mask   = (const int*)  d_in[1];
  const int*   sidx   = (const int*)  d_in[2];
  const float* pe     = (const float*)d_in[3];
  const float* w_ih_f = (const float*)d_in[4];
  const float* w_hh_f = (const float*)d_in[5];
  const float* b_ih_f = (const float*)d_in[6];
  const float* b_hh_f = (const float*)d_in[7];
  const float* w_ih_b = (const float*)d_in[8];
  const float* w_hh_b = (const float*)d_in[9];
  const float* b_ih_b = (const float*)d_in[10];
  const float* b_hh_b = (const float*)d_in[11];
  const float* sw1 = (const float*)d_in[12]; const float* sb1 = (const float*)d_in[13];
  const float* sw2 = (const float*)d_in[14]; const float* sb2 = (const float*)d_in[15];
  const float* ew1 = (const float*)d_in[16]; const float* eb1 = (const float*)d_in[17];
  const float* ew2 = (const float*)d_in[18]; const float* eb2 = (const float*)d_in[19];
  const float* ow1 = (const float*)d_in[20]; const float* ob1 = (const float*)d_in[21];
  const float* ow2 = (const float*)d_in[22]; const float* ob2 = (const float*)d_in[23];
  const float* pw1 = (const float*)d_in[24]; const float* pb1 = (const float*)d_in[25];
  const float* pw2 = (const float*)d_in[26]; const float* pb2 = (const float*)d_in[27];

  char* wsp = (char*)d_ws; size_t off = 0;
  auto alloc = [&](size_t bytes) -> void* {
    void* p = wsp + off;
    off += (bytes + 255) & ~(size_t)255;
    return p;
  };

  unsigned short* we_bf   = (unsigned short*)alloc((size_t)4096*768*2);
  unsigned short* wihf_bf = (unsigned short*)alloc((size_t)1536*768*2);
  unsigned short* wihb_bf = (unsigned short*)alloc((size_t)1536*768*2);
  float* bc_f = (float*)alloc((size_t)1536*4);
  float* bc_b = (float*)alloc((size_t)1536*4);
  float* zerob = (float*)alloc((size_t)3072*4);
  float* xg_f = (float*)alloc((size_t)4096*1536*4);   // reused later as P_s (bf16 4096x3072)
  float* xg_b = (float*)alloc((size_t)4096*1536*4);   // reused later as P_e
  unsigned short* whh_bf = (unsigned short*)alloc((size_t)2*1536*384*2);
  unsigned int* hg = (unsigned int*)alloc((size_t)2*2*8*384*4);
  unsigned short* h_bf  = (unsigned short*)alloc((size_t)4096*768*2);
  unsigned short* sw1b  = (unsigned short*)alloc((size_t)3072*768*2);
  unsigned short* sw2b  = (unsigned short*)alloc((size_t)768*3072*2);
  unsigned short* ew1b  = (unsigned short*)alloc((size_t)3072*768*2);
  unsigned short* ew2b  = (unsigned short*)alloc((size_t)768*3072*2);
  unsigned short* ow1b  = (unsigned short*)alloc((size_t)3072*1536*2);
  unsigned short* ow2b  = (unsigned short*)alloc((size_t)768*3072*2);
  unsigned short* pw1b  = (unsigned short*)alloc((size_t)3072*768*2);
  unsigned short* pw2b  = (unsigned short*)alloc((size_t)768*3072*2);
  unsigned short* srep  = (unsigned short*)alloc((size_t)4096*768*2);
  unsigned short* erep  = (unsigned short*)alloc((size_t)4096*768*2);
  unsigned short* midb  = (unsigned short*)alloc((size_t)4096*3072*2);
  unsigned short* pe_bf = (unsigned short*)alloc((size_t)200*768*2);
  unsigned short* pmid  = (unsigned short*)alloc((size_t)200*3072*2);

  unsigned short* Ps = (unsigned short*)xg_f;   // 4096*3072*2 == 4096*1536*4
  unsigned short* Pe = (unsigned short*)xg_b;

  auto cast = [&](const float* s, unsigned short* d, size_t n){
    long n4 = (long)(n / 4);
    int grid = (int)((n4 + 255) / 256);
    k_cast_bf16<<<grid, 256, 0, stream>>>(s, d, n4);
  };

  hipMemsetAsync(hg, 0, (size_t)2*2*8*384*4, stream);
  hipMemsetAsync(zerob, 0, (size_t)3072*4, stream);

  cast(we, we_bf, (size_t)4096*768);
  cast(w_ih_f, wihf_bf, (size_t)1536*768);
  cast(w_ih_b, wihb_bf, (size_t)1536*768);
  cast(w_hh_f, whh_bf,               (size_t)1536*384);
  cast(w_hh_b, whh_bf + 1536*384,    (size_t)1536*384);
  cast(sw1, sw1b, (size_t)3072*768);  cast(sw2, sw2b, (size_t)768*3072);
  cast(ew1, ew1b, (size_t)3072*768);  cast(ew2, ew2b, (size_t)768*3072);
  cast(ow1, ow1b, (size_t)3072*1536); cast(ow2, ow2b, (size_t)768*3072);
  cast(pw1, pw1b, (size_t)3072*768);  cast(pw2, pw2b, (size_t)768*3072);
  cast(pe, pe_bf, (size_t)200*768);

  k_biascomb<<<6, 256, 0, stream>>>(b_ih_f, b_hh_f, bc_f, 1536);
  k_biascomb<<<6, 256, 0, stream>>>(b_ih_b, b_hh_b, bc_b, 1536);

  dim3 blk(256);
  // input-gate precompute (both biases folded in), fp32 out
  k_gemm2<0,0><<<dim3(12, 32), blk, 0, stream>>>(we_bf, wihf_bf, bc_f, xg_f, 4096, 1536, 768, 768);
  k_gemm2<0,0><<<dim3(12, 32), blk, 0, stream>>>(we_bf, wihb_bf, bc_b, xg_b, 4096, 1536, 768, 768);

  k_lstm8<<<12, 512, 0, stream>>>(xg_f, xg_b, whh_bf, mask, h_bf, hg);

  // start / end MLPs; ReLU of the cat is folded into the 2nd GEMM epilogue
  k_gemm2<1,1><<<dim3(24, 32), blk, 0, stream>>>(h_bf, sw1b, sb1, midb, 4096, 3072, 768, 768);
  k_gemm2<1,1><<<dim3( 6, 32), blk, 0, stream>>>(midb, sw2b, sb2, srep, 4096,  768, 3072, 3072);
  k_gemm2<1,1><<<dim3(24, 32), blk, 0, stream>>>(h_bf, ew1b, eb1, midb, 4096, 3072, 768, 768);
  k_gemm2<1,1><<<dim3( 6, 32), blk, 0, stream>>>(midb, ew2b, eb2, erep, 4096,  768, 3072, 3072);

  // P_s = relu(srep) @ Ws^T ; P_e = relu(erep) @ We^T   (ow1 halves, ldb=1536)
  k_gemm2<0,1><<<dim3(24, 32), blk, 0, stream>>>(srep, ow1b,       zerob, Ps, 4096, 3072, 768, 1536);
  k_gemm2<0,1><<<dim3(24, 32), blk, 0, stream>>>(erep, ow1b + 768, zerob, Pe, 4096, 3072, 768, 1536);

  float* outp = (float*)d_out;
  // fused gather + add + bias + relu + out-projection over all 8 batches
  k_gout<<<dim3(6, 384), blk, 0, stream>>>(Ps, Pe, sidx, ob1, ow2b, ob2, outp);

  // prompt projection
  k_gemm2<1,1><<<dim3(24, 2), blk, 0, stream>>>(pe_bf, pw1b, pb1, pmid, 200, 3072, 768, 768);
  k_gemm2<0,0><<<dim3( 6, 2), blk, 0, stream>>>(pmid, pw2b, pb2,
                                                outp + (size_t)37748736, 200, 768, 3072, 3072);
}

// Round 10
// 1998.191 us; speedup vs baseline: 1.5420x; 1.5420x over previous
//
#include <hip/hip_runtime.h>
#include <hip/hip_bf16.h>
#include <stdint.h>

#define B_ 8
#define L_ 512
#define H_ 768
#define WW_ 12
#define C_ 25
#define S_ (L_*WW_)   // 6144
#define HH 384        // H/2
#define G4 1536       // 4*HH

using bf16x8 = __attribute__((ext_vector_type(8))) short;
using f32x4  = __attribute__((ext_vector_type(4))) float;

static __device__ __forceinline__ unsigned short f2bf(float x){
  unsigned u = __float_as_uint(x);
  unsigned r = (u + 0x7FFFu + ((u >> 16) & 1u)) >> 16;
  return (unsigned short)r;
}
static __device__ __forceinline__ float bflo(unsigned u){ return __uint_as_float(u << 16); }
static __device__ __forceinline__ float bfhi(unsigned u){ return __uint_as_float(u & 0xFFFF0000u); }

static __device__ __forceinline__ float sigmoid_f(float x){
  x = fminf(15.f, fmaxf(-15.f, x));
  return 1.f / (1.f + __expf(-x));
}
static __device__ __forceinline__ float tanh_f(float x){
  x = fminf(15.f, fmaxf(-15.f, x));
  float e = __expf(-2.f * x);
  return (1.f - e) / (1.f + e);
}

// global -> LDS direct DMA, 16 B per lane (dest = wave-uniform base + lane*16)
static __device__ __forceinline__ void gl_lds16(const unsigned short* g, unsigned short* l){
  __builtin_amdgcn_global_load_lds(
      (const __attribute__((address_space(1))) unsigned int*)g,
      (__attribute__((address_space(3))) unsigned int*)l,
      16, 0, 0);
}

// ---------------- fp32 -> bf16 cast (n multiple of 4) ----------------
__global__ void k_cast_bf16(const float* __restrict__ s, unsigned short* __restrict__ d, long n4){
  long i = (long)blockIdx.x * blockDim.x + threadIdx.x;
  if (i >= n4) return;
  float4 v = reinterpret_cast<const float4*>(s)[i];
  ushort4 o;
  o.x = f2bf(v.x); o.y = f2bf(v.y); o.z = f2bf(v.z); o.w = f2bf(v.w);
  reinterpret_cast<ushort4*>(d)[i] = o;
}

__global__ void k_biascomb(const float* __restrict__ a, const float* __restrict__ b,
                           float* __restrict__ o, int n){
  int i = blockIdx.x * blockDim.x + threadIdx.x;
  if (i < n) o[i] = a[i] + b[i];
}

// ---------------- LDS-staged NT GEMM (m97 structure) ----------------
template<int ACT, int OUTBF>
__global__ __launch_bounds__(256) void k_gemm2(
    const unsigned short* __restrict__ A, const unsigned short* __restrict__ Bm,
    const float* __restrict__ bias, void* __restrict__ Cout,
    int M, int N, int K, int ldb)
{
  __shared__ unsigned short Al[128 * 64];
  __shared__ unsigned short Bl[128 * 64];

  const int tid  = threadIdx.x;
  const int lane = tid & 63;
  const int wave = tid >> 6;
  const int wr = wave >> 1, wc = wave & 1;
  const int l16 = lane & 15, lq = lane >> 4;
  const int m0 = blockIdx.y * 128;
  const int n0 = blockIdx.x * 128;

  const int r_ = tid >> 3;
  const int p_ = tid & 7;
  const int cS = ((p_ ^ (r_ & 7)) * 8);
  const unsigned short* Asrc[4];
  const unsigned short* Bsrc[4];
  #pragma unroll
  for (int i = 0; i < 4; i++){
    int ra = m0 + i * 32 + r_; ra = ra < M ? ra : (M - 1);
    Asrc[i] = A + (size_t)ra * K + cS;
    int rb = n0 + i * 32 + r_; rb = rb < N ? rb : (N - 1);
    Bsrc[i] = Bm + (size_t)rb * ldb + cS;
  }

  f32x4 acc[4][4];
  #pragma unroll
  for (int a = 0; a < 4; a++)
    #pragma unroll
    for (int b = 0; b < 4; b++)
      acc[a][b] = (f32x4)0.f;

  const int sw0 = ((0 * 4 + lq) ^ (l16 & 7)) * 16;
  const int sw1 = ((1 * 4 + lq) ^ (l16 & 7)) * 16;
  const int aBase = (wr * 64 + l16) * 128;
  const int bBase = (wc * 64 + l16) * 128;

  for (int k0 = 0; k0 < K; k0 += 64){
    #pragma unroll
    for (int i = 0; i < 4; i++)
      gl_lds16(Asrc[i] + k0, Al + i * 2048 + tid * 8);
    #pragma unroll
    for (int i = 0; i < 4; i++)
      gl_lds16(Bsrc[i] + k0, Bl + i * 2048 + tid * 8);
    __syncthreads();

    #pragma unroll
    for (int kk = 0; kk < 2; kk++){
      const int sw = kk ? sw1 : sw0;
      bf16x8 av[4], bv[4];
      #pragma unroll
      for (int mi = 0; mi < 4; mi++)
        av[mi] = *reinterpret_cast<const bf16x8*>((const char*)Al + aBase + mi * 2048 + sw);
      #pragma unroll
      for (int ni = 0; ni < 4; ni++)
        bv[ni] = *reinterpret_cast<const bf16x8*>((const char*)Bl + bBase + ni * 2048 + sw);
      #pragma unroll
      for (int mi = 0; mi < 4; mi++)
        #pragma unroll
        for (int ni = 0; ni < 4; ni++)
          acc[mi][ni] = __builtin_amdgcn_mfma_f32_16x16x32_bf16(av[mi], bv[ni], acc[mi][ni], 0, 0, 0);
    }
    __syncthreads();
  }

  #pragma unroll
  for (int mi = 0; mi < 4; mi++){
    #pragma unroll
    for (int r = 0; r < 4; r++){
      int row = m0 + wr * 64 + mi * 16 + lq * 4 + r;
      if (row >= M) continue;
      #pragma unroll
      for (int ni = 0; ni < 4; ni++){
        int col = n0 + wc * 64 + ni * 16 + l16;
        float v = acc[mi][ni][r] + bias[col];
        if (ACT) v = v > 0.f ? v : 0.f;
        if (OUTBF) ((unsigned short*)Cout)[(size_t)row * N + col] = f2bf(v);
        else       ((float*)Cout)[(size_t)row * N + col] = v;
      }
    }
  }
}

// ---------------- fused out-projection GEMM, 128x256 tile ------------------
// out[49152][768] = (relu(Ps[gather i0] + Pe[gather i1] + b1)) @ ow2^T + b2
// N-tile widened to 256: A gather+add+relu prep done 3x (was 6x) and hidden
// under 2x MFMA per barrier. 4 waves, wave = 64 rows x 128 cols (acc 4x8).
__global__ __launch_bounds__(256) void k_gout(
    const unsigned short* __restrict__ Ps, const unsigned short* __restrict__ Pe,
    const int* __restrict__ sidx, const float* __restrict__ b1,
    const unsigned short* __restrict__ Bw, const float* __restrict__ b2,
    float* __restrict__ out)
{
  __shared__ unsigned short Al[128 * 64];   // 16 KB
  __shared__ unsigned short Bl[256 * 64];   // 32 KB
  __shared__ int idx2[128][2];

  const int tid  = threadIdx.x;
  const int lane = tid & 63;
  const int wave = tid >> 6;
  const int wr = wave >> 1, wc = wave & 1;
  const int l16 = lane & 15, lq = lane >> 4;
  const int tm = blockIdx.y;            // 0..383
  const int b  = tm / 48;
  const int s0 = (tm % 48) * 128;
  const int n0 = blockIdx.x * 256;      // 0..2 -> 768

  if (tid < 128){
    int s = s0 + tid;
    int i0 = sidx[((size_t)b * S_ + s) * 2 + 0];
    int i1 = sidx[((size_t)b * S_ + s) * 2 + 1];
    idx2[tid][0] = min(max(i0, 0), L_ - 1);
    idx2[tid][1] = min(max(i1, 0), L_ - 1);
  }
  __syncthreads();

  const int r_ = tid >> 3;
  const int p_ = tid & 7;
  const int cS = ((p_ ^ (r_ & 7)) * 8);
  const unsigned short* Bsrc[8];
  const unsigned short* As0[4];
  const unsigned short* As1[4];
  #pragma unroll
  for (int i = 0; i < 8; i++)
    Bsrc[i] = Bw + (size_t)(n0 + i * 32 + r_) * 3072 + cS;
  #pragma unroll
  for (int i = 0; i < 4; i++){
    int rr = i * 32 + r_;
    As0[i] = Ps + (size_t)(b * L_ + idx2[rr][0]) * 3072 + cS;
    As1[i] = Pe + (size_t)(b * L_ + idx2[rr][1]) * 3072 + cS;
  }

  f32x4 acc[4][8];
  #pragma unroll
  for (int a = 0; a < 4; a++)
    #pragma unroll
    for (int c = 0; c < 8; c++)
      acc[a][c] = (f32x4)0.f;

  const int sw0 = ((0 * 4 + lq) ^ (l16 & 7)) * 16;
  const int sw1 = ((1 * 4 + lq) ^ (l16 & 7)) * 16;
  const int aBase = (wr * 64 + l16) * 128;
  const int bBase = (wc * 128 + l16) * 128;   // wave col-half: wc*128 rows of B

  for (int k0 = 0; k0 < 3072; k0 += 64){
    #pragma unroll
    for (int i = 0; i < 8; i++)
      gl_lds16(Bsrc[i] + k0, Bl + i * 2048 + tid * 8);
    float4 bb0 = *reinterpret_cast<const float4*>(b1 + k0 + cS);
    float4 bb1 = *reinterpret_cast<const float4*>(b1 + k0 + cS + 4);
    #pragma unroll
    for (int i = 0; i < 4; i++){
      uint4 va = *reinterpret_cast<const uint4*>(As0[i] + k0);
      uint4 ve = *reinterpret_cast<const uint4*>(As1[i] + k0);
      float f[8];
      f[0] = bflo(va.x) + bflo(ve.x) + bb0.x; f[1] = bfhi(va.x) + bfhi(ve.x) + bb0.y;
      f[2] = bflo(va.y) + bflo(ve.y) + bb0.z; f[3] = bfhi(va.y) + bfhi(ve.y) + bb0.w;
      f[4] = bflo(va.z) + bflo(ve.z) + bb1.x; f[5] = bfhi(va.z) + bfhi(ve.z) + bb1.y;
      f[6] = bflo(va.w) + bflo(ve.w) + bb1.z; f[7] = bfhi(va.w) + bfhi(ve.w) + bb1.w;
      unsigned short e[8];
      #pragma unroll
      for (int j = 0; j < 8; j++){ float v = f[j] > 0.f ? f[j] : 0.f; e[j] = f2bf(v); }
      uint4 rr;
      rr.x = (unsigned)e[0] | ((unsigned)e[1] << 16);
      rr.y = (unsigned)e[2] | ((unsigned)e[3] << 16);
      rr.z = (unsigned)e[4] | ((unsigned)e[5] << 16);
      rr.w = (unsigned)e[6] | ((unsigned)e[7] << 16);
      *reinterpret_cast<uint4*>(Al + i * 2048 + tid * 8) = rr;
    }
    __syncthreads();

    #pragma unroll
    for (int kk = 0; kk < 2; kk++){
      const int sw = kk ? sw1 : sw0;
      bf16x8 av[4], bv[8];
      #pragma unroll
      for (int mi = 0; mi < 4; mi++)
        av[mi] = *reinterpret_cast<const bf16x8*>((const char*)Al + aBase + mi * 2048 + sw);
      #pragma unroll
      for (int ni = 0; ni < 8; ni++)
        bv[ni] = *reinterpret_cast<const bf16x8*>((const char*)Bl + bBase + ni * 2048 + sw);
      #pragma unroll
      for (int mi = 0; mi < 4; mi++)
        #pragma unroll
        for (int ni = 0; ni < 8; ni++)
          acc[mi][ni] = __builtin_amdgcn_mfma_f32_16x16x32_bf16(av[mi], bv[ni], acc[mi][ni], 0, 0, 0);
    }
    __syncthreads();
  }

  #pragma unroll
  for (int mi = 0; mi < 4; mi++){
    #pragma unroll
    for (int r = 0; r < 4; r++){
      size_t row = (size_t)tm * 128 + wr * 64 + mi * 16 + lq * 4 + r;
      #pragma unroll
      for (int ni = 0; ni < 8; ni++){
        int col = n0 + wc * 128 + ni * 16 + l16;
        out[row * 768 + col] = acc[mi][ni][r] + b2[col];
      }
    }
  }
}

// ---------------- distributed LSTM v7 (verbatim round-8 winner, 978us) ------
static __device__ __forceinline__ unsigned long long ald8(const unsigned long long* p){
  return __hip_atomic_load(p, __ATOMIC_RELAXED, __HIP_MEMORY_SCOPE_AGENT);
}

__global__ __launch_bounds__(512, 2) void k_lstm7(
    const float* __restrict__ xgf, const float* __restrict__ xgb,
    const unsigned short* __restrict__ Wbf,   // [2][1536][384] bf16
    const int* __restrict__ mask,
    unsigned short* __restrict__ hbf,         // [4096][768] bf16 out (masked)
    unsigned int* __restrict__ hg)            // [2][2][3072] tagged words (pre-zeroed)
{
  const int dir  = blockIdx.x / 6;
  const int part = blockIdx.x % 6;
  const int tid  = threadIdx.x;
  const int lane = tid & 63;
  const int w    = tid >> 6;            // wave 0..7
  const int l16  = lane & 15, lq = lane >> 4;

  __shared__ alignas(16) unsigned short hls[8 * HH];   // 6 KB, XOR-swizzled
  __shared__ float gsl[256 * 9];                        // padded gate staging

  const float* xg = dir ? xgb : xgf;
  const unsigned short* Wg = Wbf + (size_t)dir * G4 * HH;
  unsigned int* hgd = hg + dir * 2 * (8 * HH);

  // resident W_hh B-frags: wave w covers local gate-rows w*32 .. w*32+31
  bf16x8 bfr0[12], bfr1[12];
  {
    int r0 = w * 32 + l16;
    int r1 = w * 32 + 16 + l16;
    int g0 = r0 >> 6, j0u = r0 & 63;
    int g1 = r1 >> 6, j1u = r1 & 63;
    const unsigned short* p0 = Wg + ((size_t)g0 * HH + part * 64 + j0u) * HH + lq * 8;
    const unsigned short* p1 = Wg + ((size_t)g1 * HH + part * 64 + j1u) * HH + lq * 8;
    #pragma unroll
    for (int kf = 0; kf < 12; kf++){
      bfr0[kf] = *reinterpret_cast<const bf16x8*>(p0 + kf * 32);
      bfr1[kf] = *reinterpret_cast<const bf16x8*>(p1 + kf * 32);
    }
  }

  if (tid < 384) reinterpret_cast<uint4*>(hls)[tid] = uint4{0,0,0,0};

  const int cb = tid >> 6;          // combine: batch = wave
  const int cj = tid & 63;          // combine: unit within part
  const int cu = part * 64 + cj;    // global unit
  float c_state = 0.f;

  const int w0  = tid * 6;
  const int rb  = w0 / HH;
  const int ru  = w0 % HH;

  // prefetch xg/mask for step 0
  float xi, xf, xgg, xo, mvf;
  {
    const int t0 = dir ? (L_ - 1) : 0;
    const float* xr = xg + ((size_t)cb * L_ + t0) * G4;
    xi = xr[cu]; xf = xr[HH + cu]; xgg = xr[2 * HH + cu]; xo = xr[3 * HH + cu];
    mvf = (float)mask[cb * L_ + t0];
  }

  __syncthreads();

  for (int s = 0; s < L_; s++){
    const int t = dir ? (L_ - 1 - s) : s;

    // issue next step's xg loads (consumed next iteration -> full-step latency hiding)
    float nxi = 0.f, nxf = 0.f, nxg = 0.f, nxo = 0.f, nmv = 0.f;
    if (s + 1 < L_){
      const int tn = dir ? (L_ - 2 - s) : (s + 1);
      const float* xr = xg + ((size_t)cb * L_ + tn) * G4;
      nxi = xr[cu]; nxf = xr[HH + cu]; nxg = xr[2 * HH + cu]; nxo = xr[3 * HH + cu];
      nmv = (float)mask[cb * L_ + tn];
    }

    if (s > 0){
      const unsigned long long tg = (unsigned long long)s;
      const unsigned long long* P =
        reinterpret_cast<const unsigned long long*>(hgd + ((s - 1) & 1) * (8 * HH) + w0);
      unsigned long long v0 = ald8(P), v1 = ald8(P + 1), v2 = ald8(P + 2);
      // combined retry: one round-trip refreshes all three words
      for (;;){
        bool ok0 = (((v0 >> 16) & 0xFFFFull) == tg) & ((v0 >> 48) == tg);
        bool ok1 = (((v1 >> 16) & 0xFFFFull) == tg) & ((v1 >> 48) == tg);
        bool ok2 = (((v2 >> 16) & 0xFFFFull) == tg) & ((v2 >> 48) == tg);
        if (ok0 & ok1 & ok2) break;
        v0 = ald8(P); v1 = ald8(P + 1); v2 = ald8(P + 2);
      }
      unsigned p01 = (unsigned)(v0 & 0xFFFFu) | ((unsigned)((v0 >> 32) & 0xFFFFu) << 16);
      unsigned p23 = (unsigned)(v1 & 0xFFFFu) | ((unsigned)((v1 >> 32) & 0xFFFFu) << 16);
      unsigned p45 = (unsigned)(v2 & 0xFFFFu) | ((unsigned)((v2 >> 32) & 0xFFFFu) << 16);
      *reinterpret_cast<unsigned*>((char*)hls + ((rb * 768 + (ru    ) * 2) ^ (rb << 4))) = p01;
      *reinterpret_cast<unsigned*>((char*)hls + ((rb * 768 + (ru + 2) * 2) ^ (rb << 4))) = p23;
      *reinterpret_cast<unsigned*>((char*)hls + ((rb * 768 + (ru + 4) * 2) ^ (rb << 4))) = p45;
    }
    __syncthreads();

    // gates = h @ Wslice^T : per wave 2 n-tiles x 12 k-frags
    f32x4 acc0 = (f32x4)0.f, acc1 = (f32x4)0.f;
    const int arow = l16 & 7;
    #pragma unroll
    for (int kf = 0; kf < 12; kf++){
      int by = (arow * 768 + kf * 64 + lq * 16) ^ (arow << 4);
      bf16x8 a = *reinterpret_cast<const bf16x8*>((const char*)hls + by);
      acc0 = __builtin_amdgcn_mfma_f32_16x16x32_bf16(a, bfr0[kf], acc0, 0, 0, 0);
      acc1 = __builtin_amdgcn_mfma_f32_16x16x32_bf16(a, bfr1[kf], acc1, 0, 0, 0);
    }
    if (lq < 2){
      int n0r = w * 32 + l16;
      int n1r = w * 32 + 16 + l16;
      #pragma unroll
      for (int r = 0; r < 4; r++){
        gsl[n0r * 9 + lq * 4 + r] = acc0[r];
        gsl[n1r * 9 + lq * 4 + r] = acc1[r];
      }
    }
    __syncthreads();

    // combine: thread = (batch cb, unit cj)
    {
      float gi = gsl[(0 * 64 + cj) * 9 + cb] + xi;
      float gf = gsl[(1 * 64 + cj) * 9 + cb] + xf;
      float gg = gsl[(2 * 64 + cj) * 9 + cb] + xgg;
      float go = gsl[(3 * 64 + cj) * 9 + cb] + xo;
      c_state = sigmoid_f(gf) * c_state + sigmoid_f(gi) * tanh_f(gg);
      float h = sigmoid_f(go) * tanh_f(c_state);
      unsigned short hb = f2bf(h);
      *reinterpret_cast<unsigned short*>((char*)hls + ((cb * 768 + cu * 2) ^ (cb << 4))) = hb;
      unsigned word = ((unsigned)(s + 1) << 16) | (unsigned)hb;
      __hip_atomic_store(&hgd[(s & 1) * (8 * HH) + cb * HH + cu], word,
                         __ATOMIC_RELAXED, __HIP_MEMORY_SCOPE_AGENT);
      hbf[((size_t)cb * L_ + t) * H_ + dir * HH + cu] = f2bf(h * mvf);
    }

    xi = nxi; xf = nxf; xgg = nxg; xo = nxo; mvf = nmv;
  }
}

extern "C" void kernel_launch(void* const* d_in, const int* in_sizes, int n_in,
                              void* d_out, int out_size, void* d_ws, size_t ws_size,
                              hipStream_t stream)
{
  (void)in_sizes; (void)n_in; (void)out_size; (void)ws_size;
  const float* we     = (const float*)d_in[0];
  const int*   mask   = (const int*)  d_in[1];
  const int*   sidx   = (const int*)  d_in[2];
  const float* pe     = (const float*)d_in[3];
  const float* w_ih_f = (const float*)d_in[4];
  const float* w_hh_f = (const float*)d_in[5];
  const float* b_ih_f = (const float*)d_in[6];
  const float* b_hh_f = (const float*)d_in[7];
  const float* w_ih_b = (const float*)d_in[8];
  const float* w_hh_b = (const float*)d_in[9];
  const float* b_ih_b = (const float*)d_in[10];
  const float* b_hh_b = (const float*)d_in[11];
  const float* sw1 = (const float*)d_in[12]; const float* sb1 = (const float*)d_in[13];
  const float* sw2 = (const float*)d_in[14]; const float* sb2 = (const float*)d_in[15];
  const float* ew1 = (const float*)d_in[16]; const float* eb1 = (const float*)d_in[17];
  const float* ew2 = (const float*)d_in[18]; const float* eb2 = (const float*)d_in[19];
  const float* ow1 = (const float*)d_in[20]; const float* ob1 = (const float*)d_in[21];
  const float* ow2 = (const float*)d_in[22]; const float* ob2 = (const float*)d_in[23];
  const float* pw1 = (const float*)d_in[24]; const float* pb1 = (const float*)d_in[25];
  const float* pw2 = (const float*)d_in[26]; const float* pb2 = (const float*)d_in[27];

  char* wsp = (char*)d_ws; size_t off = 0;
  auto alloc = [&](size_t bytes) -> void* {
    void* p = wsp + off;
    off += (bytes + 255) & ~(size_t)255;
    return p;
  };

  unsigned short* we_bf   = (unsigned short*)alloc((size_t)4096*768*2);
  unsigned short* wihf_bf = (unsigned short*)alloc((size_t)1536*768*2);
  unsigned short* wihb_bf = (unsigned short*)alloc((size_t)1536*768*2);
  float* bc_f = (float*)alloc((size_t)1536*4);
  float* bc_b = (float*)alloc((size_t)1536*4);
  float* zerob = (float*)alloc((size_t)3072*4);
  float* xg_f = (float*)alloc((size_t)4096*1536*4);   // reused later as P_s (bf16 4096x3072)
  float* xg_b = (float*)alloc((size_t)4096*1536*4);   // reused later as P_e
  unsigned short* whh_bf = (unsigned short*)alloc((size_t)2*1536*384*2);
  unsigned int* hg = (unsigned int*)alloc((size_t)2*2*8*384*4);
  unsigned short* h_bf  = (unsigned short*)alloc((size_t)4096*768*2);
  unsigned short* sw1b  = (unsigned short*)alloc((size_t)3072*768*2);
  unsigned short* sw2b  = (unsigned short*)alloc((size_t)768*3072*2);
  unsigned short* ew1b  = (unsigned short*)alloc((size_t)3072*768*2);
  unsigned short* ew2b  = (unsigned short*)alloc((size_t)768*3072*2);
  unsigned short* ow1b  = (unsigned short*)alloc((size_t)3072*1536*2);
  unsigned short* ow2b  = (unsigned short*)alloc((size_t)768*3072*2);
  unsigned short* pw1b  = (unsigned short*)alloc((size_t)3072*768*2);
  unsigned short* pw2b  = (unsigned short*)alloc((size_t)768*3072*2);
  unsigned short* srep  = (unsigned short*)alloc((size_t)4096*768*2);
  unsigned short* erep  = (unsigned short*)alloc((size_t)4096*768*2);
  unsigned short* midb  = (unsigned short*)alloc((size_t)4096*3072*2);
  unsigned short* pe_bf = (unsigned short*)alloc((size_t)200*768*2);
  unsigned short* pmid  = (unsigned short*)alloc((size_t)200*3072*2);

  unsigned short* Ps = (unsigned short*)xg_f;   // 4096*3072*2 == 4096*1536*4
  unsigned short* Pe = (unsigned short*)xg_b;

  auto cast = [&](const float* s, unsigned short* d, size_t n){
    long n4 = (long)(n / 4);
    int grid = (int)((n4 + 255) / 256);
    k_cast_bf16<<<grid, 256, 0, stream>>>(s, d, n4);
  };

  hipMemsetAsync(hg, 0, (size_t)2*2*8*384*4, stream);
  hipMemsetAsync(zerob, 0, (size_t)3072*4, stream);

  cast(we, we_bf, (size_t)4096*768);
  cast(w_ih_f, wihf_bf, (size_t)1536*768);
  cast(w_ih_b, wihb_bf, (size_t)1536*768);
  cast(w_hh_f, whh_bf,               (size_t)1536*384);
  cast(w_hh_b, whh_bf + 1536*384,    (size_t)1536*384);
  cast(sw1, sw1b, (size_t)3072*768);  cast(sw2, sw2b, (size_t)768*3072);
  cast(ew1, ew1b, (size_t)3072*768);  cast(ew2, ew2b, (size_t)768*3072);
  cast(ow1, ow1b, (size_t)3072*1536); cast(ow2, ow2b, (size_t)768*3072);
  cast(pw1, pw1b, (size_t)3072*768);  cast(pw2, pw2b, (size_t)768*3072);
  cast(pe, pe_bf, (size_t)200*768);

  k_biascomb<<<6, 256, 0, stream>>>(b_ih_f, b_hh_f, bc_f, 1536);
  k_biascomb<<<6, 256, 0, stream>>>(b_ih_b, b_hh_b, bc_b, 1536);

  dim3 blk(256);
  // input-gate precompute (both biases folded in), fp32 out
  k_gemm2<0,0><<<dim3(12, 32), blk, 0, stream>>>(we_bf, wihf_bf, bc_f, xg_f, 4096, 1536, 768, 768);
  k_gemm2<0,0><<<dim3(12, 32), blk, 0, stream>>>(we_bf, wihb_bf, bc_b, xg_b, 4096, 1536, 768, 768);

  k_lstm7<<<12, 512, 0, stream>>>(xg_f, xg_b, whh_bf, mask, h_bf, hg);

  // start / end MLPs; ReLU of the cat is folded into the 2nd GEMM epilogue
  k_gemm2<1,1><<<dim3(24, 32), blk, 0, stream>>>(h_bf, sw1b, sb1, midb, 4096, 3072, 768, 768);
  k_gemm2<1,1><<<dim3( 6, 32), blk, 0, stream>>>(midb, sw2b, sb2, srep, 4096,  768, 3072, 3072);
  k_gemm2<1,1><<<dim3(24, 32), blk, 0, stream>>>(h_bf, ew1b, eb1, midb, 4096, 3072, 768, 768);
  k_gemm2<1,1><<<dim3( 6, 32), blk, 0, stream>>>(midb, ew2b, eb2, erep, 4096,  768, 3072, 3072);

  // P_s = relu(srep) @ Ws^T ; P_e = relu(erep) @ We^T   (ow1 halves, ldb=1536)
  k_gemm2<0,1><<<dim3(24, 32), blk, 0, stream>>>(srep, ow1b,       zerob, Ps, 4096, 3072, 768, 1536);
  k_gemm2<0,1><<<dim3(24, 32), blk, 0, stream>>>(erep, ow1b + 768, zerob, Pe, 4096, 3072, 768, 1536);

  float* outp = (float*)d_out;
  // fused gather + add + bias + relu + out-projection, 128x256 tiles
  k_gout<<<dim3(3, 384), blk, 0, stream>>>(Ps, Pe, sidx, ob1, ow2b, ob2, outp);

  // prompt projection
  k_gemm2<1,1><<<dim3(24, 2), blk, 0, stream>>>(pe_bf, pw1b, pb1, pmid, 200, 3072, 768, 768);
  k_gemm2<0,0><<<dim3( 6, 2), blk, 0, stream>>>(pmid, pw2b, pb2,
                                                outp + (size_t)37748736, 200, 768, 3072, 3072);
}

// Round 11
// 1859.821 us; speedup vs baseline: 1.6567x; 1.0744x over previous
//
#include <hip/hip_runtime.h>
#include <hip/hip_bf16.h>
#include <stdint.h>

#define B_ 8
#define L_ 512
#define H_ 768
#define WW_ 12
#define C_ 25
#define S_ (L_*WW_)   // 6144
#define HH 384        // H/2
#define G4 1536       // 4*HH

using bf16x8 = __attribute__((ext_vector_type(8))) short;
using f32x4  = __attribute__((ext_vector_type(4))) float;

static __device__ __forceinline__ unsigned short f2bf(float x){
  unsigned u = __float_as_uint(x);
  unsigned r = (u + 0x7FFFu + ((u >> 16) & 1u)) >> 16;
  return (unsigned short)r;
}
static __device__ __forceinline__ float bflo(unsigned u){ return __uint_as_float(u << 16); }
static __device__ __forceinline__ float bfhi(unsigned u){ return __uint_as_float(u & 0xFFFF0000u); }

static __device__ __forceinline__ float sigmoid_f(float x){
  x = fminf(15.f, fmaxf(-15.f, x));
  return 1.f / (1.f + __expf(-x));
}
static __device__ __forceinline__ float tanh_f(float x){
  x = fminf(15.f, fmaxf(-15.f, x));
  float e = __expf(-2.f * x);
  return (1.f - e) / (1.f + e);
}

// global -> LDS direct DMA, 16 B per lane (dest = wave-uniform base + lane*16)
static __device__ __forceinline__ void gl_lds16(const unsigned short* g, unsigned short* l){
  __builtin_amdgcn_global_load_lds(
      (const __attribute__((address_space(1))) unsigned int*)g,
      (__attribute__((address_space(3))) unsigned int*)l,
      16, 0, 0);
}

// ---------------- fp32 -> bf16 cast (n multiple of 4) ----------------
__global__ void k_cast_bf16(const float* __restrict__ s, unsigned short* __restrict__ d, long n4){
  long i = (long)blockIdx.x * blockDim.x + threadIdx.x;
  if (i >= n4) return;
  float4 v = reinterpret_cast<const float4*>(s)[i];
  ushort4 o;
  o.x = f2bf(v.x); o.y = f2bf(v.y); o.z = f2bf(v.z); o.w = f2bf(v.w);
  reinterpret_cast<ushort4*>(d)[i] = o;
}

__global__ void k_biascomb(const float* __restrict__ a, const float* __restrict__ b,
                           float* __restrict__ o, int n){
  int i = blockIdx.x * blockDim.x + threadIdx.x;
  if (i < n) o[i] = a[i] + b[i];
}

// ---------------- LDS-staged NT GEMM (m97 structure) ----------------
// C[M,N] = act(A[M,K] @ B[N,K]^T + bias); A row stride lda (>=K), B row stride ldb.
template<int ACT, int OUTBF>
__global__ __launch_bounds__(256) void k_gemm2(
    const unsigned short* __restrict__ A, const unsigned short* __restrict__ Bm,
    const float* __restrict__ bias, void* __restrict__ Cout,
    int M, int N, int K, int lda, int ldb)
{
  __shared__ unsigned short Al[128 * 64];
  __shared__ unsigned short Bl[128 * 64];

  const int tid  = threadIdx.x;
  const int lane = tid & 63;
  const int wave = tid >> 6;
  const int wr = wave >> 1, wc = wave & 1;
  const int l16 = lane & 15, lq = lane >> 4;
  const int m0 = blockIdx.y * 128;
  const int n0 = blockIdx.x * 128;

  const int r_ = tid >> 3;
  const int p_ = tid & 7;
  const int cS = ((p_ ^ (r_ & 7)) * 8);
  const unsigned short* Asrc[4];
  const unsigned short* Bsrc[4];
  #pragma unroll
  for (int i = 0; i < 4; i++){
    int ra = m0 + i * 32 + r_; ra = ra < M ? ra : (M - 1);
    Asrc[i] = A + (size_t)ra * lda + cS;
    int rb = n0 + i * 32 + r_; rb = rb < N ? rb : (N - 1);
    Bsrc[i] = Bm + (size_t)rb * ldb + cS;
  }

  f32x4 acc[4][4];
  #pragma unroll
  for (int a = 0; a < 4; a++)
    #pragma unroll
    for (int b = 0; b < 4; b++)
      acc[a][b] = (f32x4)0.f;

  const int sw0 = ((0 * 4 + lq) ^ (l16 & 7)) * 16;
  const int sw1 = ((1 * 4 + lq) ^ (l16 & 7)) * 16;
  const int aBase = (wr * 64 + l16) * 128;
  const int bBase = (wc * 64 + l16) * 128;

  for (int k0 = 0; k0 < K; k0 += 64){
    #pragma unroll
    for (int i = 0; i < 4; i++)
      gl_lds16(Asrc[i] + k0, Al + i * 2048 + tid * 8);
    #pragma unroll
    for (int i = 0; i < 4; i++)
      gl_lds16(Bsrc[i] + k0, Bl + i * 2048 + tid * 8);
    __syncthreads();

    #pragma unroll
    for (int kk = 0; kk < 2; kk++){
      const int sw = kk ? sw1 : sw0;
      bf16x8 av[4], bv[4];
      #pragma unroll
      for (int mi = 0; mi < 4; mi++)
        av[mi] = *reinterpret_cast<const bf16x8*>((const char*)Al + aBase + mi * 2048 + sw);
      #pragma unroll
      for (int ni = 0; ni < 4; ni++)
        bv[ni] = *reinterpret_cast<const bf16x8*>((const char*)Bl + bBase + ni * 2048 + sw);
      #pragma unroll
      for (int mi = 0; mi < 4; mi++)
        #pragma unroll
        for (int ni = 0; ni < 4; ni++)
          acc[mi][ni] = __builtin_amdgcn_mfma_f32_16x16x32_bf16(av[mi], bv[ni], acc[mi][ni], 0, 0, 0);
    }
    __syncthreads();
  }

  #pragma unroll
  for (int mi = 0; mi < 4; mi++){
    #pragma unroll
    for (int r = 0; r < 4; r++){
      int row = m0 + wr * 64 + mi * 16 + lq * 4 + r;
      if (row >= M) continue;
      #pragma unroll
      for (int ni = 0; ni < 4; ni++){
        int col = n0 + wc * 64 + ni * 16 + l16;
        float v = acc[mi][ni][r] + bias[col];
        if (ACT) v = v > 0.f ? v : 0.f;
        if (OUTBF) ((unsigned short*)Cout)[(size_t)row * N + col] = f2bf(v);
        else       ((float*)Cout)[(size_t)row * N + col] = v;
      }
    }
  }
}

// ---------------- fused out-projection GEMM (round-8 geometry + T14) -------
// out[49152][768] = (relu(Ps[gather i0] + Pe[gather i1] + b1)) @ ow2^T + b2
// A gathers prefetched one K-step ahead into registers: gather latency hides
// under MFMA + the (already required) vmcnt(0) barrier drain for B gl_lds.
__global__ __launch_bounds__(256) void k_gout(
    const unsigned short* __restrict__ Ps, const unsigned short* __restrict__ Pe,
    const int* __restrict__ sidx, const float* __restrict__ b1,
    const unsigned short* __restrict__ Bw, const float* __restrict__ b2,
    float* __restrict__ out)
{
  __shared__ unsigned short Al[128 * 64];
  __shared__ unsigned short Bl[128 * 64];
  __shared__ int idx2[128][2];

  const int tid  = threadIdx.x;
  const int lane = tid & 63;
  const int wave = tid >> 6;
  const int wr = wave >> 1, wc = wave & 1;
  const int l16 = lane & 15, lq = lane >> 4;
  const int tm = blockIdx.y;            // 0..383
  const int b  = tm / 48;
  const int s0 = (tm % 48) * 128;
  const int n0 = blockIdx.x * 128;      // 0..5 -> 768

  if (tid < 128){
    int s = s0 + tid;
    int i0 = sidx[((size_t)b * S_ + s) * 2 + 0];
    int i1 = sidx[((size_t)b * S_ + s) * 2 + 1];
    idx2[tid][0] = min(max(i0, 0), L_ - 1);
    idx2[tid][1] = min(max(i1, 0), L_ - 1);
  }
  __syncthreads();

  const int r_ = tid >> 3;
  const int p_ = tid & 7;
  const int cS = ((p_ ^ (r_ & 7)) * 8);
  const unsigned short* Bsrc[4];
  const unsigned short* As0[4];
  const unsigned short* As1[4];
  #pragma unroll
  for (int i = 0; i < 4; i++){
    Bsrc[i] = Bw + (size_t)(n0 + i * 32 + r_) * 3072 + cS;
    int rr = i * 32 + r_;
    As0[i] = Ps + (size_t)(b * L_ + idx2[rr][0]) * 3072 + cS;
    As1[i] = Pe + (size_t)(b * L_ + idx2[rr][1]) * 3072 + cS;
  }

  f32x4 acc[4][4];
  #pragma unroll
  for (int a = 0; a < 4; a++)
    #pragma unroll
    for (int c = 0; c < 4; c++)
      acc[a][c] = (f32x4)0.f;

  const int sw0 = ((0 * 4 + lq) ^ (l16 & 7)) * 16;
  const int sw1 = ((1 * 4 + lq) ^ (l16 & 7)) * 16;
  const int aBase = (wr * 64 + l16) * 128;
  const int bBase = (wc * 64 + l16) * 128;

  // T14 prefetch registers: K-step k0's gathers loaded during k0-64
  uint4 vaR[4], veR[4];
  float4 bbR0, bbR1;
  #pragma unroll
  for (int i = 0; i < 4; i++){
    vaR[i] = *reinterpret_cast<const uint4*>(As0[i]);
    veR[i] = *reinterpret_cast<const uint4*>(As1[i]);
  }
  bbR0 = *reinterpret_cast<const float4*>(b1 + cS);
  bbR1 = *reinterpret_cast<const float4*>(b1 + cS + 4);

  for (int k0 = 0; k0 < 3072; k0 += 64){
    #pragma unroll
    for (int i = 0; i < 4; i++)
      gl_lds16(Bsrc[i] + k0, Bl + i * 2048 + tid * 8);

    // A-prep from prefetched registers
    #pragma unroll
    for (int i = 0; i < 4; i++){
      uint4 va = vaR[i];
      uint4 ve = veR[i];
      float f[8];
      f[0] = bflo(va.x) + bflo(ve.x) + bbR0.x; f[1] = bfhi(va.x) + bfhi(ve.x) + bbR0.y;
      f[2] = bflo(va.y) + bflo(ve.y) + bbR0.z; f[3] = bfhi(va.y) + bfhi(ve.y) + bbR0.w;
      f[4] = bflo(va.z) + bflo(ve.z) + bbR1.x; f[5] = bfhi(va.z) + bfhi(ve.z) + bbR1.y;
      f[6] = bflo(va.w) + bflo(ve.w) + bbR1.z; f[7] = bfhi(va.w) + bfhi(ve.w) + bbR1.w;
      unsigned short e[8];
      #pragma unroll
      for (int j = 0; j < 8; j++){ float v = f[j] > 0.f ? f[j] : 0.f; e[j] = f2bf(v); }
      uint4 rr;
      rr.x = (unsigned)e[0] | ((unsigned)e[1] << 16);
      rr.y = (unsigned)e[2] | ((unsigned)e[3] << 16);
      rr.z = (unsigned)e[4] | ((unsigned)e[5] << 16);
      rr.w = (unsigned)e[6] | ((unsigned)e[7] << 16);
      *reinterpret_cast<uint4*>(Al + i * 2048 + tid * 8) = rr;
    }

    // issue next K-step's gathers (consumed next iteration)
    if (k0 + 64 < 3072){
      #pragma unroll
      for (int i = 0; i < 4; i++){
        vaR[i] = *reinterpret_cast<const uint4*>(As0[i] + k0 + 64);
        veR[i] = *reinterpret_cast<const uint4*>(As1[i] + k0 + 64);
      }
      bbR0 = *reinterpret_cast<const float4*>(b1 + k0 + 64 + cS);
      bbR1 = *reinterpret_cast<const float4*>(b1 + k0 + 64 + cS + 4);
    }
    __syncthreads();

    #pragma unroll
    for (int kk = 0; kk < 2; kk++){
      const int sw = kk ? sw1 : sw0;
      bf16x8 av[4], bv[4];
      #pragma unroll
      for (int mi = 0; mi < 4; mi++)
        av[mi] = *reinterpret_cast<const bf16x8*>((const char*)Al + aBase + mi * 2048 + sw);
      #pragma unroll
      for (int ni = 0; ni < 4; ni++)
        bv[ni] = *reinterpret_cast<const bf16x8*>((const char*)Bl + bBase + ni * 2048 + sw);
      #pragma unroll
      for (int mi = 0; mi < 4; mi++)
        #pragma unroll
        for (int ni = 0; ni < 4; ni++)
          acc[mi][ni] = __builtin_amdgcn_mfma_f32_16x16x32_bf16(av[mi], bv[ni], acc[mi][ni], 0, 0, 0);
    }
    __syncthreads();
  }

  #pragma unroll
  for (int mi = 0; mi < 4; mi++){
    #pragma unroll
    for (int r = 0; r < 4; r++){
      size_t row = (size_t)tm * 128 + wr * 64 + mi * 16 + lq * 4 + r;
      #pragma unroll
      for (int ni = 0; ni < 4; ni++){
        int col = n0 + wc * 64 + ni * 16 + l16;
        out[row * 768 + col] = acc[mi][ni][r] + b2[col];
      }
    }
  }
}

// ---------------- distributed LSTM v7 (round-8 winner; xg stride 3072) ------
static __device__ __forceinline__ unsigned long long ald8(const unsigned long long* p){
  return __hip_atomic_load(p, __ATOMIC_RELAXED, __HIP_MEMORY_SCOPE_AGENT);
}

__global__ __launch_bounds__(512, 2) void k_lstm7(
    const float* __restrict__ xgc,            // [4096][3072]: [fwd 1536 | bwd 1536]
    const unsigned short* __restrict__ Wbf,   // [2][1536][384] bf16
    const int* __restrict__ mask,
    unsigned short* __restrict__ hbf,         // [4096][768] bf16 out (masked)
    unsigned int* __restrict__ hg)            // [2][2][3072] tagged words (pre-zeroed)
{
  const int dir  = blockIdx.x / 6;
  const int part = blockIdx.x % 6;
  const int tid  = threadIdx.x;
  const int lane = tid & 63;
  const int w    = tid >> 6;            // wave 0..7
  const int l16  = lane & 15, lq = lane >> 4;

  __shared__ alignas(16) unsigned short hls[8 * HH];   // 6 KB, XOR-swizzled
  __shared__ float gsl[256 * 9];                        // padded gate staging

  const float* xg = xgc + dir * 1536;
  const unsigned short* Wg = Wbf + (size_t)dir * G4 * HH;
  unsigned int* hgd = hg + dir * 2 * (8 * HH);

  // resident W_hh B-frags: wave w covers local gate-rows w*32 .. w*32+31
  bf16x8 bfr0[12], bfr1[12];
  {
    int r0 = w * 32 + l16;
    int r1 = w * 32 + 16 + l16;
    int g0 = r0 >> 6, j0u = r0 & 63;
    int g1 = r1 >> 6, j1u = r1 & 63;
    const unsigned short* p0 = Wg + ((size_t)g0 * HH + part * 64 + j0u) * HH + lq * 8;
    const unsigned short* p1 = Wg + ((size_t)g1 * HH + part * 64 + j1u) * HH + lq * 8;
    #pragma unroll
    for (int kf = 0; kf < 12; kf++){
      bfr0[kf] = *reinterpret_cast<const bf16x8*>(p0 + kf * 32);
      bfr1[kf] = *reinterpret_cast<const bf16x8*>(p1 + kf * 32);
    }
  }

  if (tid < 384) reinterpret_cast<uint4*>(hls)[tid] = uint4{0,0,0,0};

  const int cb = tid >> 6;          // combine: batch = wave
  const int cj = tid & 63;          // combine: unit within part
  const int cu = part * 64 + cj;    // global unit
  float c_state = 0.f;

  const int w0  = tid * 6;
  const int rb  = w0 / HH;
  const int ru  = w0 % HH;

  // prefetch xg/mask for step 0
  float xi, xf, xgg, xo, mvf;
  {
    const int t0 = dir ? (L_ - 1) : 0;
    const float* xr = xg + ((size_t)cb * L_ + t0) * 3072;
    xi = xr[cu]; xf = xr[HH + cu]; xgg = xr[2 * HH + cu]; xo = xr[3 * HH + cu];
    mvf = (float)mask[cb * L_ + t0];
  }

  __syncthreads();

  for (int s = 0; s < L_; s++){
    const int t = dir ? (L_ - 1 - s) : s;

    // issue next step's xg loads (consumed next iteration -> full-step latency hiding)
    float nxi = 0.f, nxf = 0.f, nxg = 0.f, nxo = 0.f, nmv = 0.f;
    if (s + 1 < L_){
      const int tn = dir ? (L_ - 2 - s) : (s + 1);
      const float* xr = xg + ((size_t)cb * L_ + tn) * 3072;
      nxi = xr[cu]; nxf = xr[HH + cu]; nxg = xr[2 * HH + cu]; nxo = xr[3 * HH + cu];
      nmv = (float)mask[cb * L_ + tn];
    }

    if (s > 0){
      const unsigned long long tg = (unsigned long long)s;
      const unsigned long long* P =
        reinterpret_cast<const unsigned long long*>(hgd + ((s - 1) & 1) * (8 * HH) + w0);
      unsigned long long v0 = ald8(P), v1 = ald8(P + 1), v2 = ald8(P + 2);
      // combined retry: one round-trip refreshes all three words
      for (;;){
        bool ok0 = (((v0 >> 16) & 0xFFFFull) == tg) & ((v0 >> 48) == tg);
        bool ok1 = (((v1 >> 16) & 0xFFFFull) == tg) & ((v1 >> 48) == tg);
        bool ok2 = (((v2 >> 16) & 0xFFFFull) == tg) & ((v2 >> 48) == tg);
        if (ok0 & ok1 & ok2) break;
        v0 = ald8(P); v1 = ald8(P + 1); v2 = ald8(P + 2);
      }
      unsigned p01 = (unsigned)(v0 & 0xFFFFu) | ((unsigned)((v0 >> 32) & 0xFFFFu) << 16);
      unsigned p23 = (unsigned)(v1 & 0xFFFFu) | ((unsigned)((v1 >> 32) & 0xFFFFu) << 16);
      unsigned p45 = (unsigned)(v2 & 0xFFFFu) | ((unsigned)((v2 >> 32) & 0xFFFFu) << 16);
      *reinterpret_cast<unsigned*>((char*)hls + ((rb * 768 + (ru    ) * 2) ^ (rb << 4))) = p01;
      *reinterpret_cast<unsigned*>((char*)hls + ((rb * 768 + (ru + 2) * 2) ^ (rb << 4))) = p23;
      *reinterpret_cast<unsigned*>((char*)hls + ((rb * 768 + (ru + 4) * 2) ^ (rb << 4))) = p45;
    }
    __syncthreads();

    // gates = h @ Wslice^T : per wave 2 n-tiles x 12 k-frags
    f32x4 acc0 = (f32x4)0.f, acc1 = (f32x4)0.f;
    const int arow = l16 & 7;
    #pragma unroll
    for (int kf = 0; kf < 12; kf++){
      int by = (arow * 768 + kf * 64 + lq * 16) ^ (arow << 4);
      bf16x8 a = *reinterpret_cast<const bf16x8*>((const char*)hls + by);
      acc0 = __builtin_amdgcn_mfma_f32_16x16x32_bf16(a, bfr0[kf], acc0, 0, 0, 0);
      acc1 = __builtin_amdgcn_mfma_f32_16x16x32_bf16(a, bfr1[kf], acc1, 0, 0, 0);
    }
    if (lq < 2){
      int n0r = w * 32 + l16;
      int n1r = w * 32 + 16 + l16;
      #pragma unroll
      for (int r = 0; r < 4; r++){
        gsl[n0r * 9 + lq * 4 + r] = acc0[r];
        gsl[n1r * 9 + lq * 4 + r] = acc1[r];
      }
    }
    __syncthreads();

    // combine: thread = (batch cb, unit cj)
    {
      float gi = gsl[(0 * 64 + cj) * 9 + cb] + xi;
      float gf = gsl[(1 * 64 + cj) * 9 + cb] + xf;
      float gg = gsl[(2 * 64 + cj) * 9 + cb] + xgg;
      float go = gsl[(3 * 64 + cj) * 9 + cb] + xo;
      c_state = sigmoid_f(gf) * c_state + sigmoid_f(gi) * tanh_f(gg);
      float h = sigmoid_f(go) * tanh_f(c_state);
      unsigned short hb = f2bf(h);
      *reinterpret_cast<unsigned short*>((char*)hls + ((cb * 768 + cu * 2) ^ (cb << 4))) = hb;
      unsigned word = ((unsigned)(s + 1) << 16) | (unsigned)hb;
      __hip_atomic_store(&hgd[(s & 1) * (8 * HH) + cb * HH + cu], word,
                         __ATOMIC_RELAXED, __HIP_MEMORY_SCOPE_AGENT);
      hbf[((size_t)cb * L_ + t) * H_ + dir * HH + cu] = f2bf(h * mvf);
    }

    xi = nxi; xf = nxf; xgg = nxg; xo = nxo; mvf = nmv;
  }
}

extern "C" void kernel_launch(void* const* d_in, const int* in_sizes, int n_in,
                              void* d_out, int out_size, void* d_ws, size_t ws_size,
                              hipStream_t stream)
{
  (void)in_sizes; (void)n_in; (void)out_size; (void)ws_size;
  const float* we     = (const float*)d_in[0];
  const int*   mask   = (const int*)  d_in[1];
  const int*   sidx   = (const int*)  d_in[2];
  const float* pe     = (const float*)d_in[3];
  const float* w_ih_f = (const float*)d_in[4];
  const float* w_hh_f = (const float*)d_in[5];
  const float* b_ih_f = (const float*)d_in[6];
  const float* b_hh_f = (const float*)d_in[7];
  const float* w_ih_b = (const float*)d_in[8];
  const float* w_hh_b = (const float*)d_in[9];
  const float* b_ih_b = (const float*)d_in[10];
  const float* b_hh_b = (const float*)d_in[11];
  const float* sw1 = (const float*)d_in[12]; const float* sb1 = (const float*)d_in[13];
  const float* sw2 = (const float*)d_in[14]; const float* sb2 = (const float*)d_in[15];
  const float* ew1 = (const float*)d_in[16]; const float* eb1 = (const float*)d_in[17];
  const float* ew2 = (const float*)d_in[18]; const float* eb2 = (const float*)d_in[19];
  const float* ow1 = (const float*)d_in[20]; const float* ob1 = (const float*)d_in[21];
  const float* ow2 = (const float*)d_in[22]; const float* ob2 = (const float*)d_in[23];
  const float* pw1 = (const float*)d_in[24]; const float* pb1 = (const float*)d_in[25];
  const float* pw2 = (const float*)d_in[26]; const float* pb2 = (const float*)d_in[27];

  char* wsp = (char*)d_ws; size_t off = 0;
  auto alloc = [&](size_t bytes) -> void* {
    void* p = wsp + off;
    off += (bytes + 255) & ~(size_t)255;
    return p;
  };

  unsigned short* we_bf  = (unsigned short*)alloc((size_t)4096*768*2);
  unsigned short* wihc_bf= (unsigned short*)alloc((size_t)3072*768*2);   // [wihf;wihb]
  float* bcc   = (float*)alloc((size_t)3072*4);                          // [bc_f;bc_b]
  float* zerob = (float*)alloc((size_t)3072*4);
  float* sbe1  = (float*)alloc((size_t)6144*4);                          // [sb1;eb1]
  float* xgc   = (float*)alloc((size_t)4096*3072*4);   // reused later as Ps+Pe (bf16)
  unsigned short* whh_bf = (unsigned short*)alloc((size_t)2*1536*384*2);
  unsigned int* hg = (unsigned int*)alloc((size_t)2*2*8*384*4);
  unsigned short* h_bf  = (unsigned short*)alloc((size_t)4096*768*2);
  unsigned short* swe1b = (unsigned short*)alloc((size_t)6144*768*2);    // [sw1;ew1]
  unsigned short* sw2b  = (unsigned short*)alloc((size_t)768*3072*2);
  unsigned short* ew2b  = (unsigned short*)alloc((size_t)768*3072*2);
  unsigned short* ow1b  = (unsigned short*)alloc((size_t)3072*1536*2);
  unsigned short* ow2b  = (unsigned short*)alloc((size_t)768*3072*2);
  unsigned short* pw1b  = (unsigned short*)alloc((size_t)3072*768*2);
  unsigned short* pw2b  = (unsigned short*)alloc((size_t)768*3072*2);
  unsigned short* srep  = (unsigned short*)alloc((size_t)4096*768*2);
  unsigned short* erep  = (unsigned short*)alloc((size_t)4096*768*2);
  unsigned short* midc  = (unsigned short*)alloc((size_t)4096*6144*2);   // [mid_s|mid_e] cols
  unsigned short* pe_bf = (unsigned short*)alloc((size_t)200*768*2);
  unsigned short* pmid  = (unsigned short*)alloc((size_t)200*3072*2);

  unsigned short* Ps = (unsigned short*)xgc;                    // 4096*3072 bf16
  unsigned short* Pe = (unsigned short*)xgc + (size_t)4096*3072;

  auto cast = [&](const float* s, unsigned short* d, size_t n){
    long n4 = (long)(n / 4);
    int grid = (int)((n4 + 255) / 256);
    k_cast_bf16<<<grid, 256, 0, stream>>>(s, d, n4);
  };

  hipMemsetAsync(hg, 0, (size_t)2*2*8*384*4, stream);
  hipMemsetAsync(zerob, 0, (size_t)3072*4, stream);
  hipMemcpyAsync(sbe1,        sb1, (size_t)3072*4, hipMemcpyDeviceToDevice, stream);
  hipMemcpyAsync(sbe1 + 3072, eb1, (size_t)3072*4, hipMemcpyDeviceToDevice, stream);

  cast(we, we_bf, (size_t)4096*768);
  cast(w_ih_f, wihc_bf,             (size_t)1536*768);
  cast(w_ih_b, wihc_bf + 1536*768,  (size_t)1536*768);
  cast(w_hh_f, whh_bf,               (size_t)1536*384);
  cast(w_hh_b, whh_bf + 1536*384,    (size_t)1536*384);
  cast(sw1, swe1b,             (size_t)3072*768);
  cast(ew1, swe1b + 3072*768,  (size_t)3072*768);
  cast(sw2, sw2b, (size_t)768*3072);
  cast(ew2, ew2b, (size_t)768*3072);
  cast(ow1, ow1b, (size_t)3072*1536); cast(ow2, ow2b, (size_t)768*3072);
  cast(pw1, pw1b, (size_t)3072*768);  cast(pw2, pw2b, (size_t)768*3072);
  cast(pe, pe_bf, (size_t)200*768);

  k_biascomb<<<6, 256, 0, stream>>>(b_ih_f, b_hh_f, bcc, 1536);
  k_biascomb<<<6, 256, 0, stream>>>(b_ih_b, b_hh_b, bcc + 1536, 1536);

  dim3 blk(256);
  // input-gate precompute, both directions in ONE GEMM (N=3072), fp32 out
  k_gemm2<0,0><<<dim3(24, 32), blk, 0, stream>>>(we_bf, wihc_bf, bcc, xgc, 4096, 3072, 768, 768, 768);

  k_lstm7<<<12, 512, 0, stream>>>(xgc, whh_bf, mask, h_bf, hg);

  // start+end first-layer MLP in ONE GEMM (N=6144) -> midc [4096][6144]
  k_gemm2<1,1><<<dim3(48, 32), blk, 0, stream>>>(h_bf, swe1b, sbe1, midc, 4096, 6144, 768, 768, 768);
  // second layers read column-halves of midc (lda=6144); relu of cat folded in
  k_gemm2<1,1><<<dim3(6, 32), blk, 0, stream>>>(midc,        sw2b, sb2, srep, 4096, 768, 3072, 6144, 3072);
  k_gemm2<1,1><<<dim3(6, 32), blk, 0, stream>>>(midc + 3072, ew2b, eb2, erep, 4096, 768, 3072, 6144, 3072);

  // P_s = relu(srep) @ Ws^T ; P_e = relu(erep) @ We^T   (ow1 halves, ldb=1536)
  k_gemm2<0,1><<<dim3(24, 32), blk, 0, stream>>>(srep, ow1b,       zerob, Ps, 4096, 3072, 768, 768, 1536);
  k_gemm2<0,1><<<dim3(24, 32), blk, 0, stream>>>(erep, ow1b + 768, zerob, Pe, 4096, 3072, 768, 768, 1536);

  float* outp = (float*)d_out;
  // fused gather + add + bias + relu + out-projection (128x128 tiles, T14 prefetch)
  k_gout<<<dim3(6, 384), blk, 0, stream>>>(Ps, Pe, sidx, ob1, ow2b, ob2, outp);

  // prompt projection
  k_gemm2<1,1><<<dim3(24, 2), blk, 0, stream>>>(pe_bf, pw1b, pb1, pmid, 200, 3072, 768, 768, 768);
  k_gemm2<0,0><<<dim3( 6, 2), blk, 0, stream>>>(pmid, pw2b, pb2,
                                                outp + (size_t)37748736, 200, 768, 3072, 3072, 3072);
}

// Round 12
// 1836.765 us; speedup vs baseline: 1.6775x; 1.0126x over previous
//
#include <hip/hip_runtime.h>
#include <hip/hip_bf16.h>
#include <stdint.h>

#define B_ 8
#define L_ 512
#define H_ 768
#define WW_ 12
#define C_ 25
#define S_ (L_*WW_)   // 6144
#define HH 384        // H/2
#define G4 1536       // 4*HH

using bf16x8 = __attribute__((ext_vector_type(8))) short;
using f32x4  = __attribute__((ext_vector_type(4))) float;

static __device__ __forceinline__ unsigned short f2bf(float x){
  unsigned u = __float_as_uint(x);
  unsigned r = (u + 0x7FFFu + ((u >> 16) & 1u)) >> 16;
  return (unsigned short)r;
}
static __device__ __forceinline__ float bflo(unsigned u){ return __uint_as_float(u << 16); }
static __device__ __forceinline__ float bfhi(unsigned u){ return __uint_as_float(u & 0xFFFF0000u); }

static __device__ __forceinline__ float sigmoid_f(float x){
  x = fminf(15.f, fmaxf(-15.f, x));
  return 1.f / (1.f + __expf(-x));
}
static __device__ __forceinline__ float tanh_f(float x){
  x = fminf(15.f, fmaxf(-15.f, x));
  float e = __expf(-2.f * x);
  return (1.f - e) / (1.f + e);
}

// global -> LDS direct DMA, 16 B per lane (dest = wave-uniform base + lane*16)
static __device__ __forceinline__ void gl_lds16(const unsigned short* g, unsigned short* l){
  __builtin_amdgcn_global_load_lds(
      (const __attribute__((address_space(1))) unsigned int*)g,
      (__attribute__((address_space(3))) unsigned int*)l,
      16, 0, 0);
}

// ---------------- batched fp32 -> bf16 cast (14 segments, one launch) -------
struct CastArgs {
  const float* s[14];
  unsigned short* d[14];
  long cum[15];   // cumulative n4 offsets
};

__global__ __launch_bounds__(256) void k_cast_multi(CastArgs a, long total){
  long i = (long)blockIdx.x * blockDim.x + threadIdx.x;
  if (i >= total) return;
  int seg = 0;
  while (i >= a.cum[seg + 1]) seg++;
  long j = i - a.cum[seg];
  float4 v = reinterpret_cast<const float4*>(a.s[seg])[j];
  ushort4 o;
  o.x = f2bf(v.x); o.y = f2bf(v.y); o.z = f2bf(v.z); o.w = f2bf(v.w);
  reinterpret_cast<ushort4*>(a.d[seg])[j] = o;
}

__global__ void k_biascomb(const float* __restrict__ a, const float* __restrict__ b,
                           float* __restrict__ o, int n){
  int i = blockIdx.x * blockDim.x + threadIdx.x;
  if (i < n) o[i] = a[i] + b[i];
}

// ---------------- LDS-staged NT GEMM (m97 structure) ----------------
// C[M,N] = act(A[M,K] @ B[N,K]^T + bias); A row stride lda, B row stride ldb.
// GX=0: grid(x=n,y=m). GX=1: grid(x=m,y=n) -> same-A blocks get id-stride
// divisible by 8 (same XCD under round-robin dispatch) for A L2-reuse.
template<int ACT, int OUTBF, int GX = 0>
__global__ __launch_bounds__(256) void k_gemm2(
    const unsigned short* __restrict__ A, const unsigned short* __restrict__ Bm,
    const float* __restrict__ bias, void* __restrict__ Cout,
    int M, int N, int K, int lda, int ldb)
{
  __shared__ unsigned short Al[128 * 64];
  __shared__ unsigned short Bl[128 * 64];

  const int tid  = threadIdx.x;
  const int lane = tid & 63;
  const int wave = tid >> 6;
  const int wr = wave >> 1, wc = wave & 1;
  const int l16 = lane & 15, lq = lane >> 4;
  const int m0 = (GX == 0 ? blockIdx.y : blockIdx.x) * 128;
  const int n0 = (GX == 0 ? blockIdx.x : blockIdx.y) * 128;

  const int r_ = tid >> 3;
  const int p_ = tid & 7;
  const int cS = ((p_ ^ (r_ & 7)) * 8);
  const unsigned short* Asrc[4];
  const unsigned short* Bsrc[4];
  #pragma unroll
  for (int i = 0; i < 4; i++){
    int ra = m0 + i * 32 + r_; ra = ra < M ? ra : (M - 1);
    Asrc[i] = A + (size_t)ra * lda + cS;
    int rb = n0 + i * 32 + r_; rb = rb < N ? rb : (N - 1);
    Bsrc[i] = Bm + (size_t)rb * ldb + cS;
  }

  f32x4 acc[4][4];
  #pragma unroll
  for (int a = 0; a < 4; a++)
    #pragma unroll
    for (int b = 0; b < 4; b++)
      acc[a][b] = (f32x4)0.f;

  const int sw0 = ((0 * 4 + lq) ^ (l16 & 7)) * 16;
  const int sw1 = ((1 * 4 + lq) ^ (l16 & 7)) * 16;
  const int aBase = (wr * 64 + l16) * 128;
  const int bBase = (wc * 64 + l16) * 128;

  for (int k0 = 0; k0 < K; k0 += 64){
    #pragma unroll
    for (int i = 0; i < 4; i++)
      gl_lds16(Asrc[i] + k0, Al + i * 2048 + tid * 8);
    #pragma unroll
    for (int i = 0; i < 4; i++)
      gl_lds16(Bsrc[i] + k0, Bl + i * 2048 + tid * 8);
    __syncthreads();

    #pragma unroll
    for (int kk = 0; kk < 2; kk++){
      const int sw = kk ? sw1 : sw0;
      bf16x8 av[4], bv[4];
      #pragma unroll
      for (int mi = 0; mi < 4; mi++)
        av[mi] = *reinterpret_cast<const bf16x8*>((const char*)Al + aBase + mi * 2048 + sw);
      #pragma unroll
      for (int ni = 0; ni < 4; ni++)
        bv[ni] = *reinterpret_cast<const bf16x8*>((const char*)Bl + bBase + ni * 2048 + sw);
      #pragma unroll
      for (int mi = 0; mi < 4; mi++)
        #pragma unroll
        for (int ni = 0; ni < 4; ni++)
          acc[mi][ni] = __builtin_amdgcn_mfma_f32_16x16x32_bf16(av[mi], bv[ni], acc[mi][ni], 0, 0, 0);
    }
    __syncthreads();
  }

  #pragma unroll
  for (int mi = 0; mi < 4; mi++){
    #pragma unroll
    for (int r = 0; r < 4; r++){
      int row = m0 + wr * 64 + mi * 16 + lq * 4 + r;
      if (row >= M) continue;
      #pragma unroll
      for (int ni = 0; ni < 4; ni++){
        int col = n0 + wc * 64 + ni * 16 + l16;
        float v = acc[mi][ni][r] + bias[col];
        if (ACT) v = v > 0.f ? v : 0.f;
        if (OUTBF) ((unsigned short*)Cout)[(size_t)row * N + col] = f2bf(v);
        else       ((float*)Cout)[(size_t)row * N + col] = v;
      }
    }
  }
}

// ---------------- fused out-projection GEMM (XCD-colocated n-blocks) -------
// out[49152][768] = (relu(Ps[gather i0] + Pe[gather i1] + b1)) @ ow2^T + b2
// 1D grid 2304; decode puts the 6 n-blocks sharing one row-tile's gathers on
// the SAME XCD at adjacent slots -> gathered A rows hit L2 instead of L3 x6.
__global__ __launch_bounds__(256) void k_gout(
    const unsigned short* __restrict__ Ps, const unsigned short* __restrict__ Pe,
    const int* __restrict__ sidx, const float* __restrict__ b1,
    const unsigned short* __restrict__ Bw, const float* __restrict__ b2,
    float* __restrict__ out)
{
  __shared__ unsigned short Al[128 * 64];
  __shared__ unsigned short Bl[128 * 64];
  __shared__ int idx2[128][2];

  const int tid  = threadIdx.x;
  const int lane = tid & 63;
  const int wave = tid >> 6;
  const int wr = wave >> 1, wc = wave & 1;
  const int l16 = lane & 15, lq = lane >> 4;

  // XCD-colocating decode: xcd = wg%8 fixed by dispatch round-robin; the 6
  // n-blocks of row-tile tm occupy consecutive slots within that XCD.
  const int wg   = blockIdx.x;          // 0..2303
  const int xcd  = wg & 7;
  const int slot = wg >> 3;             // 0..287
  const int nblk = slot % 6;
  const int tm   = xcd + 8 * (slot / 6);   // 0..383
  const int b  = tm / 48;
  const int s0 = (tm % 48) * 128;
  const int n0 = nblk * 128;

  if (tid < 128){
    int s = s0 + tid;
    int i0 = sidx[((size_t)b * S_ + s) * 2 + 0];
    int i1 = sidx[((size_t)b * S_ + s) * 2 + 1];
    idx2[tid][0] = min(max(i0, 0), L_ - 1);
    idx2[tid][1] = min(max(i1, 0), L_ - 1);
  }
  __syncthreads();

  const int r_ = tid >> 3;
  const int p_ = tid & 7;
  const int cS = ((p_ ^ (r_ & 7)) * 8);
  const unsigned short* Bsrc[4];
  const unsigned short* As0[4];
  const unsigned short* As1[4];
  #pragma unroll
  for (int i = 0; i < 4; i++){
    Bsrc[i] = Bw + (size_t)(n0 + i * 32 + r_) * 3072 + cS;
    int rr = i * 32 + r_;
    As0[i] = Ps + (size_t)(b * L_ + idx2[rr][0]) * 3072 + cS;
    As1[i] = Pe + (size_t)(b * L_ + idx2[rr][1]) * 3072 + cS;
  }

  f32x4 acc[4][4];
  #pragma unroll
  for (int a = 0; a < 4; a++)
    #pragma unroll
    for (int c = 0; c < 4; c++)
      acc[a][c] = (f32x4)0.f;

  const int sw0 = ((0 * 4 + lq) ^ (l16 & 7)) * 16;
  const int sw1 = ((1 * 4 + lq) ^ (l16 & 7)) * 16;
  const int aBase = (wr * 64 + l16) * 128;
  const int bBase = (wc * 64 + l16) * 128;

  // one-K-step-ahead gather prefetch (kept from round 11; neutral-to-positive)
  uint4 vaR[4], veR[4];
  float4 bbR0, bbR1;
  #pragma unroll
  for (int i = 0; i < 4; i++){
    vaR[i] = *reinterpret_cast<const uint4*>(As0[i]);
    veR[i] = *reinterpret_cast<const uint4*>(As1[i]);
  }
  bbR0 = *reinterpret_cast<const float4*>(b1 + cS);
  bbR1 = *reinterpret_cast<const float4*>(b1 + cS + 4);

  for (int k0 = 0; k0 < 3072; k0 += 64){
    #pragma unroll
    for (int i = 0; i < 4; i++)
      gl_lds16(Bsrc[i] + k0, Bl + i * 2048 + tid * 8);

    #pragma unroll
    for (int i = 0; i < 4; i++){
      uint4 va = vaR[i];
      uint4 ve = veR[i];
      float f[8];
      f[0] = bflo(va.x) + bflo(ve.x) + bbR0.x; f[1] = bfhi(va.x) + bfhi(ve.x) + bbR0.y;
      f[2] = bflo(va.y) + bflo(ve.y) + bbR0.z; f[3] = bfhi(va.y) + bfhi(ve.y) + bbR0.w;
      f[4] = bflo(va.z) + bflo(ve.z) + bbR1.x; f[5] = bfhi(va.z) + bfhi(ve.z) + bbR1.y;
      f[6] = bflo(va.w) + bflo(ve.w) + bbR1.z; f[7] = bfhi(va.w) + bfhi(ve.w) + bbR1.w;
      unsigned short e[8];
      #pragma unroll
      for (int j = 0; j < 8; j++){ float v = f[j] > 0.f ? f[j] : 0.f; e[j] = f2bf(v); }
      uint4 rr;
      rr.x = (unsigned)e[0] | ((unsigned)e[1] << 16);
      rr.y = (unsigned)e[2] | ((unsigned)e[3] << 16);
      rr.z = (unsigned)e[4] | ((unsigned)e[5] << 16);
      rr.w = (unsigned)e[6] | ((unsigned)e[7] << 16);
      *reinterpret_cast<uint4*>(Al + i * 2048 + tid * 8) = rr;
    }

    if (k0 + 64 < 3072){
      #pragma unroll
      for (int i = 0; i < 4; i++){
        vaR[i] = *reinterpret_cast<const uint4*>(As0[i] + k0 + 64);
        veR[i] = *reinterpret_cast<const uint4*>(As1[i] + k0 + 64);
      }
      bbR0 = *reinterpret_cast<const float4*>(b1 + k0 + 64 + cS);
      bbR1 = *reinterpret_cast<const float4*>(b1 + k0 + 64 + cS + 4);
    }
    __syncthreads();

    #pragma unroll
    for (int kk = 0; kk < 2; kk++){
      const int sw = kk ? sw1 : sw0;
      bf16x8 av[4], bv[4];
      #pragma unroll
      for (int mi = 0; mi < 4; mi++)
        av[mi] = *reinterpret_cast<const bf16x8*>((const char*)Al + aBase + mi * 2048 + sw);
      #pragma unroll
      for (int ni = 0; ni < 4; ni++)
        bv[ni] = *reinterpret_cast<const bf16x8*>((const char*)Bl + bBase + ni * 2048 + sw);
      #pragma unroll
      for (int mi = 0; mi < 4; mi++)
        #pragma unroll
        for (int ni = 0; ni < 4; ni++)
          acc[mi][ni] = __builtin_amdgcn_mfma_f32_16x16x32_bf16(av[mi], bv[ni], acc[mi][ni], 0, 0, 0);
    }
    __syncthreads();
  }

  #pragma unroll
  for (int mi = 0; mi < 4; mi++){
    #pragma unroll
    for (int r = 0; r < 4; r++){
      size_t row = (size_t)tm * 128 + wr * 64 + mi * 16 + lq * 4 + r;
      #pragma unroll
      for (int ni = 0; ni < 4; ni++){
        int col = n0 + wc * 64 + ni * 16 + l16;
        out[row * 768 + col] = acc[mi][ni][r] + b2[col];
      }
    }
  }
}

// ---------------- distributed LSTM v7 (round-8 winner; xg stride 3072) ------
static __device__ __forceinline__ unsigned long long ald8(const unsigned long long* p){
  return __hip_atomic_load(p, __ATOMIC_RELAXED, __HIP_MEMORY_SCOPE_AGENT);
}

__global__ __launch_bounds__(512, 2) void k_lstm7(
    const float* __restrict__ xgc,            // [4096][3072]: [fwd 1536 | bwd 1536]
    const unsigned short* __restrict__ Wbf,   // [2][1536][384] bf16
    const int* __restrict__ mask,
    unsigned short* __restrict__ hbf,         // [4096][768] bf16 out (masked)
    unsigned int* __restrict__ hg)            // [2][2][3072] tagged words (pre-zeroed)
{
  const int dir  = blockIdx.x / 6;
  const int part = blockIdx.x % 6;
  const int tid  = threadIdx.x;
  const int lane = tid & 63;
  const int w    = tid >> 6;            // wave 0..7
  const int l16  = lane & 15, lq = lane >> 4;

  __shared__ alignas(16) unsigned short hls[8 * HH];   // 6 KB, XOR-swizzled
  __shared__ float gsl[256 * 9];                        // padded gate staging

  const float* xg = xgc + dir * 1536;
  const unsigned short* Wg = Wbf + (size_t)dir * G4 * HH;
  unsigned int* hgd = hg + dir * 2 * (8 * HH);

  // resident W_hh B-frags: wave w covers local gate-rows w*32 .. w*32+31
  bf16x8 bfr0[12], bfr1[12];
  {
    int r0 = w * 32 + l16;
    int r1 = w * 32 + 16 + l16;
    int g0 = r0 >> 6, j0u = r0 & 63;
    int g1 = r1 >> 6, j1u = r1 & 63;
    const unsigned short* p0 = Wg + ((size_t)g0 * HH + part * 64 + j0u) * HH + lq * 8;
    const unsigned short* p1 = Wg + ((size_t)g1 * HH + part * 64 + j1u) * HH + lq * 8;
    #pragma unroll
    for (int kf = 0; kf < 12; kf++){
      bfr0[kf] = *reinterpret_cast<const bf16x8*>(p0 + kf * 32);
      bfr1[kf] = *reinterpret_cast<const bf16x8*>(p1 + kf * 32);
    }
  }

  if (tid < 384) reinterpret_cast<uint4*>(hls)[tid] = uint4{0,0,0,0};

  const int cb = tid >> 6;          // combine: batch = wave
  const int cj = tid & 63;          // combine: unit within part
  const int cu = part * 64 + cj;    // global unit
  float c_state = 0.f;

  const int w0  = tid * 6;
  const int rb  = w0 / HH;
  const int ru  = w0 % HH;

  // prefetch xg/mask for step 0
  float xi, xf, xgg, xo, mvf;
  {
    const int t0 = dir ? (L_ - 1) : 0;
    const float* xr = xgc + dir * 1536 + ((size_t)cb * L_ + t0) * 3072;
    xi = xr[cu]; xf = xr[HH + cu]; xgg = xr[2 * HH + cu]; xo = xr[3 * HH + cu];
    mvf = (float)mask[cb * L_ + t0];
  }

  __syncthreads();

  for (int s = 0; s < L_; s++){
    const int t = dir ? (L_ - 1 - s) : s;

    // issue next step's xg loads (consumed next iteration -> full-step latency hiding)
    float nxi = 0.f, nxf = 0.f, nxg = 0.f, nxo = 0.f, nmv = 0.f;
    if (s + 1 < L_){
      const int tn = dir ? (L_ - 2 - s) : (s + 1);
      const float* xr = xg + ((size_t)cb * L_ + tn) * 3072;
      nxi = xr[cu]; nxf = xr[HH + cu]; nxg = xr[2 * HH + cu]; nxo = xr[3 * HH + cu];
      nmv = (float)mask[cb * L_ + tn];
    }

    if (s > 0){
      const unsigned long long tg = (unsigned long long)s;
      const unsigned long long* P =
        reinterpret_cast<const unsigned long long*>(hgd + ((s - 1) & 1) * (8 * HH) + w0);
      unsigned long long v0 = ald8(P), v1 = ald8(P + 1), v2 = ald8(P + 2);
      // combined retry: one round-trip refreshes all three words
      for (;;){
        bool ok0 = (((v0 >> 16) & 0xFFFFull) == tg) & ((v0 >> 48) == tg);
        bool ok1 = (((v1 >> 16) & 0xFFFFull) == tg) & ((v1 >> 48) == tg);
        bool ok2 = (((v2 >> 16) & 0xFFFFull) == tg) & ((v2 >> 48) == tg);
        if (ok0 & ok1 & ok2) break;
        v0 = ald8(P); v1 = ald8(P + 1); v2 = ald8(P + 2);
      }
      unsigned p01 = (unsigned)(v0 & 0xFFFFu) | ((unsigned)((v0 >> 32) & 0xFFFFu) << 16);
      unsigned p23 = (unsigned)(v1 & 0xFFFFu) | ((unsigned)((v1 >> 32) & 0xFFFFu) << 16);
      unsigned p45 = (unsigned)(v2 & 0xFFFFu) | ((unsigned)((v2 >> 32) & 0xFFFFu) << 16);
      *reinterpret_cast<unsigned*>((char*)hls + ((rb * 768 + (ru    ) * 2) ^ (rb << 4))) = p01;
      *reinterpret_cast<unsigned*>((char*)hls + ((rb * 768 + (ru + 2) * 2) ^ (rb << 4))) = p23;
      *reinterpret_cast<unsigned*>((char*)hls + ((rb * 768 + (ru + 4) * 2) ^ (rb << 4))) = p45;
    }
    __syncthreads();

    // gates = h @ Wslice^T : per wave 2 n-tiles x 12 k-frags
    f32x4 acc0 = (f32x4)0.f, acc1 = (f32x4)0.f;
    const int arow = l16 & 7;
    #pragma unroll
    for (int kf = 0; kf < 12; kf++){
      int by = (arow * 768 + kf * 64 + lq * 16) ^ (arow << 4);
      bf16x8 a = *reinterpret_cast<const bf16x8*>((const char*)hls + by);
      acc0 = __builtin_amdgcn_mfma_f32_16x16x32_bf16(a, bfr0[kf], acc0, 0, 0, 0);
      acc1 = __builtin_amdgcn_mfma_f32_16x16x32_bf16(a, bfr1[kf], acc1, 0, 0, 0);
    }
    if (lq < 2){
      int n0r = w * 32 + l16;
      int n1r = w * 32 + 16 + l16;
      #pragma unroll
      for (int r = 0; r < 4; r++){
        gsl[n0r * 9 + lq * 4 + r] = acc0[r];
        gsl[n1r * 9 + lq * 4 + r] = acc1[r];
      }
    }
    __syncthreads();

    // combine: thread = (batch cb, unit cj)
    {
      float gi = gsl[(0 * 64 + cj) * 9 + cb] + xi;
      float gf = gsl[(1 * 64 + cj) * 9 + cb] + xf;
      float gg = gsl[(2 * 64 + cj) * 9 + cb] + xgg;
      float go = gsl[(3 * 64 + cj) * 9 + cb] + xo;
      c_state = sigmoid_f(gf) * c_state + sigmoid_f(gi) * tanh_f(gg);
      float h = sigmoid_f(go) * tanh_f(c_state);
      unsigned short hb = f2bf(h);
      *reinterpret_cast<unsigned short*>((char*)hls + ((cb * 768 + cu * 2) ^ (cb << 4))) = hb;
      unsigned word = ((unsigned)(s + 1) << 16) | (unsigned)hb;
      __hip_atomic_store(&hgd[(s & 1) * (8 * HH) + cb * HH + cu], word,
                         __ATOMIC_RELAXED, __HIP_MEMORY_SCOPE_AGENT);
      hbf[((size_t)cb * L_ + t) * H_ + dir * HH + cu] = f2bf(h * mvf);
    }

    xi = nxi; xf = nxf; xgg = nxg; xo = nxo; mvf = nmv;
  }
}

extern "C" void kernel_launch(void* const* d_in, const int* in_sizes, int n_in,
                              void* d_out, int out_size, void* d_ws, size_t ws_size,
                              hipStream_t stream)
{
  (void)in_sizes; (void)n_in; (void)out_size; (void)ws_size;
  const float* we     = (const float*)d_in[0];
  const int*   mask   = (const int*)  d_in[1];
  const int*   sidx   = (const int*)  d_in[2];
  const float* pe     = (const float*)d_in[3];
  const float* w_ih_f = (const float*)d_in[4];
  const float* w_hh_f = (const float*)d_in[5];
  const float* b_ih_f = (const float*)d_in[6];
  const float* b_hh_f = (const float*)d_in[7];
  const float* w_ih_b = (const float*)d_in[8];
  const float* w_hh_b = (const float*)d_in[9];
  const float* b_ih_b = (const float*)d_in[10];
  const float* b_hh_b = (const float*)d_in[11];
  const float* sw1 = (const float*)d_in[12]; const float* sb1 = (const float*)d_in[13];
  const float* sw2 = (const float*)d_in[14]; const float* sb2 = (const float*)d_in[15];
  const float* ew1 = (const float*)d_in[16]; const float* eb1 = (const float*)d_in[17];
  const float* ew2 = (const float*)d_in[18]; const float* eb2 = (const float*)d_in[19];
  const float* ow1 = (const float*)d_in[20]; const float* ob1 = (const float*)d_in[21];
  const float* ow2 = (const float*)d_in[22]; const float* ob2 = (const float*)d_in[23];
  const float* pw1 = (const float*)d_in[24]; const float* pb1 = (const float*)d_in[25];
  const float* pw2 = (const float*)d_in[26]; const float* pb2 = (const float*)d_in[27];

  char* wsp = (char*)d_ws; size_t off = 0;
  auto alloc = [&](size_t bytes) -> void* {
    void* p = wsp + off;
    off += (bytes + 255) & ~(size_t)255;
    return p;
  };

  unsigned short* we_bf  = (unsigned short*)alloc((size_t)4096*768*2);
  unsigned short* wihc_bf= (unsigned short*)alloc((size_t)3072*768*2);   // [wihf;wihb]
  float* bcc   = (float*)alloc((size_t)3072*4);                          // [bc_f;bc_b]
  float* zerob = (float*)alloc((size_t)3072*4);
  float* sbe1  = (float*)alloc((size_t)6144*4);                          // [sb1;eb1]
  float* xgc   = (float*)alloc((size_t)4096*3072*4);   // reused later as Ps+Pe (bf16)
  unsigned short* whh_bf = (unsigned short*)alloc((size_t)2*1536*384*2);
  unsigned int* hg = (unsigned int*)alloc((size_t)2*2*8*384*4);
  unsigned short* h_bf  = (unsigned short*)alloc((size_t)4096*768*2);
  unsigned short* swe1b = (unsigned short*)alloc((size_t)6144*768*2);    // [sw1;ew1]
  unsigned short* sw2b  = (unsigned short*)alloc((size_t)768*3072*2);
  unsigned short* ew2b  = (unsigned short*)alloc((size_t)768*3072*2);
  unsigned short* ow1b  = (unsigned short*)alloc((size_t)3072*1536*2);
  unsigned short* ow2b  = (unsigned short*)alloc((size_t)768*3072*2);
  unsigned short* pw1b  = (unsigned short*)alloc((size_t)3072*768*2);
  unsigned short* pw2b  = (unsigned short*)alloc((size_t)768*3072*2);
  unsigned short* srep  = (unsigned short*)alloc((size_t)4096*768*2);
  unsigned short* erep  = (unsigned short*)alloc((size_t)4096*768*2);
  unsigned short* midc  = (unsigned short*)alloc((size_t)4096*6144*2);   // [mid_s|mid_e] cols
  unsigned short* pe_bf = (unsigned short*)alloc((size_t)200*768*2);
  unsigned short* pmid  = (unsigned short*)alloc((size_t)200*3072*2);

  unsigned short* Ps = (unsigned short*)xgc;                    // 4096*3072 bf16
  unsigned short* Pe = (unsigned short*)xgc + (size_t)4096*3072;

  hipMemsetAsync(hg, 0, (size_t)2*2*8*384*4, stream);
  hipMemsetAsync(zerob, 0, (size_t)3072*4, stream);
  hipMemcpyAsync(sbe1,        sb1, (size_t)3072*4, hipMemcpyDeviceToDevice, stream);
  hipMemcpyAsync(sbe1 + 3072, eb1, (size_t)3072*4, hipMemcpyDeviceToDevice, stream);

  // ---- all fp32->bf16 casts in one launch ----
  {
    CastArgs ca;
    const float* srcs[14] = { we, w_ih_f, w_ih_b, w_hh_f, w_hh_b, sw1, ew1,
                              sw2, ew2, ow1, ow2, pw1, pw2, pe };
    unsigned short* dsts[14] = { we_bf, wihc_bf, wihc_bf + 1536*768,
                                 whh_bf, whh_bf + 1536*384,
                                 swe1b, swe1b + 3072*768,
                                 sw2b, ew2b, ow1b, ow2b, pw1b, pw2b, pe_bf };
    long n4s[14] = { 4096L*768/4, 1536L*768/4, 1536L*768/4,
                     1536L*384/4, 1536L*384/4,
                     3072L*768/4, 3072L*768/4,
                     768L*3072/4, 768L*3072/4, 3072L*1536/4, 768L*3072/4,
                     3072L*768/4, 768L*3072/4, 200L*768/4 };
    long c = 0;
    for (int i = 0; i < 14; i++){ ca.s[i] = srcs[i]; ca.d[i] = dsts[i]; ca.cum[i] = c; c += n4s[i]; }
    ca.cum[14] = c;
    int grid = (int)((c + 255) / 256);
    k_cast_multi<<<grid, 256, 0, stream>>>(ca, c);
  }

  k_biascomb<<<6, 256, 0, stream>>>(b_ih_f, b_hh_f, bcc, 1536);
  k_biascomb<<<6, 256, 0, stream>>>(b_ih_b, b_hh_b, bcc + 1536, 1536);

  dim3 blk(256);
  // input-gate precompute, both directions in ONE GEMM (N=3072), fp32 out
  k_gemm2<0,0><<<dim3(24, 32), blk, 0, stream>>>(we_bf, wihc_bf, bcc, xgc, 4096, 3072, 768, 768, 768);

  k_lstm7<<<12, 512, 0, stream>>>(xgc, whh_bf, mask, h_bf, hg);

  // start+end first-layer MLP in ONE GEMM (N=6144) -> midc [4096][6144]
  k_gemm2<1,1><<<dim3(48, 32), blk, 0, stream>>>(h_bf, swe1b, sbe1, midc, 4096, 6144, 768, 768, 768);
  // second layers: GX=1 grid(x=m,y=n) -> same-A blocks id-stride 32 (same XCD)
  k_gemm2<1,1,1><<<dim3(32, 6), blk, 0, stream>>>(midc,        sw2b, sb2, srep, 4096, 768, 3072, 6144, 3072);
  k_gemm2<1,1,1><<<dim3(32, 6), blk, 0, stream>>>(midc + 3072, ew2b, eb2, erep, 4096, 768, 3072, 6144, 3072);

  // P_s = relu(srep) @ Ws^T ; P_e = relu(erep) @ We^T   (ow1 halves, ldb=1536)
  k_gemm2<0,1><<<dim3(24, 32), blk, 0, stream>>>(srep, ow1b,       zerob, Ps, 4096, 3072, 768, 768, 1536);
  k_gemm2<0,1><<<dim3(24, 32), blk, 0, stream>>>(erep, ow1b + 768, zerob, Pe, 4096, 3072, 768, 768, 1536);

  float* outp = (float*)d_out;
  // fused gather + add + bias + relu + out-projection (XCD-colocated 1D grid)
  k_gout<<<2304, blk, 0, stream>>>(Ps, Pe, sidx, ob1, ow2b, ob2, outp);

  // prompt projection
  k_gemm2<1,1><<<dim3(24, 2), blk, 0, stream>>>(pe_bf, pw1b, pb1, pmid, 200, 3072, 768, 768, 768);
  k_gemm2<0,0><<<dim3( 6, 2), blk, 0, stream>>>(pmid, pw2b, pb2,
                                                outp + (size_t)37748736, 200, 768, 3072, 3072, 3072);
}

// Round 13
// 1681.805 us; speedup vs baseline: 1.8320x; 1.0921x over previous
//
#include <hip/hip_runtime.h>
#include <hip/hip_bf16.h>
#include <stdint.h>

#define B_ 8
#define L_ 512
#define H_ 768
#define WW_ 12
#define C_ 25
#define S_ (L_*WW_)   // 6144
#define HH 384        // H/2
#define G4 1536       // 4*HH

using bf16x8 = __attribute__((ext_vector_type(8))) short;
using f32x4  = __attribute__((ext_vector_type(4))) float;

static __device__ __forceinline__ unsigned short f2bf(float x){
  unsigned u = __float_as_uint(x);
  unsigned r = (u + 0x7FFFu + ((u >> 16) & 1u)) >> 16;
  return (unsigned short)r;
}
static __device__ __forceinline__ float bflo(unsigned u){ return __uint_as_float(u << 16); }
static __device__ __forceinline__ float bfhi(unsigned u){ return __uint_as_float(u & 0xFFFF0000u); }

static __device__ __forceinline__ float sigmoid_f(float x){
  x = fminf(15.f, fmaxf(-15.f, x));
  return 1.f / (1.f + __expf(-x));
}
static __device__ __forceinline__ float tanh_f(float x){
  x = fminf(15.f, fmaxf(-15.f, x));
  float e = __expf(-2.f * x);
  return (1.f - e) / (1.f + e);
}

// global -> LDS direct DMA, 16 B per lane (dest = wave-uniform base + lane*16)
static __device__ __forceinline__ void gl_lds16(const unsigned short* g, unsigned short* l){
  __builtin_amdgcn_global_load_lds(
      (const __attribute__((address_space(1))) unsigned int*)g,
      (__attribute__((address_space(3))) unsigned int*)l,
      16, 0, 0);
}

// ---------------- batched fp32 -> bf16 cast (14 segments, one launch) -------
struct CastArgs {
  const float* s[14];
  unsigned short* d[14];
  long cum[15];   // cumulative n4 offsets
};

__global__ __launch_bounds__(256) void k_cast_multi(CastArgs a, long total){
  long i = (long)blockIdx.x * blockDim.x + threadIdx.x;
  if (i >= total) return;
  int seg = 0;
  while (i >= a.cum[seg + 1]) seg++;
  long j = i - a.cum[seg];
  float4 v = reinterpret_cast<const float4*>(a.s[seg])[j];
  ushort4 o;
  o.x = f2bf(v.x); o.y = f2bf(v.y); o.z = f2bf(v.z); o.w = f2bf(v.w);
  reinterpret_cast<ushort4*>(a.d[seg])[j] = o;
}

// both LSTM bias sums in one launch: bcc[0:1536)=bihf+bhhf, [1536:3072)=bihb+bhhb
__global__ void k_biascomb2(const float* __restrict__ bihf, const float* __restrict__ bhhf,
                            const float* __restrict__ bihb, const float* __restrict__ bhhb,
                            float* __restrict__ o){
  int i = blockIdx.x * blockDim.x + threadIdx.x;
  if (i < 1536) o[i] = bihf[i] + bhhf[i];
  else if (i < 3072) o[i] = bihb[i - 1536] + bhhb[i - 1536];
}

// ---------------- LDS-staged NT GEMM body (m97 structure) ----------------
// C[M,N] = act(A[M,K] @ B[N,K]^T + bias); A row stride lda, B row stride ldb.
// GX=0: grid(x=n,y=m). GX=1: grid(x=m,y=n) -> same-A blocks same XCD.
template<int ACT, int OUTBF, int GX>
static __device__ __forceinline__ void gemm2_body(
    const unsigned short* __restrict__ A, const unsigned short* __restrict__ Bm,
    const float* __restrict__ bias, void* __restrict__ Cout,
    int M, int N, int K, int lda, int ldb)
{
  __shared__ unsigned short Al[128 * 64];
  __shared__ unsigned short Bl[128 * 64];

  const int tid  = threadIdx.x;
  const int lane = tid & 63;
  const int wave = tid >> 6;
  const int wr = wave >> 1, wc = wave & 1;
  const int l16 = lane & 15, lq = lane >> 4;
  const int m0 = (GX == 0 ? blockIdx.y : blockIdx.x) * 128;
  const int n0 = (GX == 0 ? blockIdx.x : blockIdx.y) * 128;

  const int r_ = tid >> 3;
  const int p_ = tid & 7;
  const int cS = ((p_ ^ (r_ & 7)) * 8);
  const unsigned short* Asrc[4];
  const unsigned short* Bsrc[4];
  #pragma unroll
  for (int i = 0; i < 4; i++){
    int ra = m0 + i * 32 + r_; ra = ra < M ? ra : (M - 1);
    Asrc[i] = A + (size_t)ra * lda + cS;
    int rb = n0 + i * 32 + r_; rb = rb < N ? rb : (N - 1);
    Bsrc[i] = Bm + (size_t)rb * ldb + cS;
  }

  f32x4 acc[4][4];
  #pragma unroll
  for (int a = 0; a < 4; a++)
    #pragma unroll
    for (int b = 0; b < 4; b++)
      acc[a][b] = (f32x4)0.f;

  const int sw0 = ((0 * 4 + lq) ^ (l16 & 7)) * 16;
  const int sw1 = ((1 * 4 + lq) ^ (l16 & 7)) * 16;
  const int aBase = (wr * 64 + l16) * 128;
  const int bBase = (wc * 64 + l16) * 128;

  for (int k0 = 0; k0 < K; k0 += 64){
    #pragma unroll
    for (int i = 0; i < 4; i++)
      gl_lds16(Asrc[i] + k0, Al + i * 2048 + tid * 8);
    #pragma unroll
    for (int i = 0; i < 4; i++)
      gl_lds16(Bsrc[i] + k0, Bl + i * 2048 + tid * 8);
    __syncthreads();

    #pragma unroll
    for (int kk = 0; kk < 2; kk++){
      const int sw = kk ? sw1 : sw0;
      bf16x8 av[4], bv[4];
      #pragma unroll
      for (int mi = 0; mi < 4; mi++)
        av[mi] = *reinterpret_cast<const bf16x8*>((const char*)Al + aBase + mi * 2048 + sw);
      #pragma unroll
      for (int ni = 0; ni < 4; ni++)
        bv[ni] = *reinterpret_cast<const bf16x8*>((const char*)Bl + bBase + ni * 2048 + sw);
      #pragma unroll
      for (int mi = 0; mi < 4; mi++)
        #pragma unroll
        for (int ni = 0; ni < 4; ni++)
          acc[mi][ni] = __builtin_amdgcn_mfma_f32_16x16x32_bf16(av[mi], bv[ni], acc[mi][ni], 0, 0, 0);
    }
    __syncthreads();
  }

  #pragma unroll
  for (int mi = 0; mi < 4; mi++){
    #pragma unroll
    for (int r = 0; r < 4; r++){
      int row = m0 + wr * 64 + mi * 16 + lq * 4 + r;
      if (row >= M) continue;
      #pragma unroll
      for (int ni = 0; ni < 4; ni++){
        int col = n0 + wc * 64 + ni * 16 + l16;
        float v = acc[mi][ni][r] + bias[col];
        if (ACT) v = v > 0.f ? v : 0.f;
        if (OUTBF) ((unsigned short*)Cout)[(size_t)row * N + col] = f2bf(v);
        else       ((float*)Cout)[(size_t)row * N + col] = v;
      }
    }
  }
}

template<int ACT, int OUTBF, int GX = 0>
__global__ __launch_bounds__(256) void k_gemm2(
    const unsigned short* A, const unsigned short* Bm,
    const float* bias, void* Cout, int M, int N, int K, int lda, int ldb)
{
  gemm2_body<ACT, OUTBF, GX>(A, Bm, bias, Cout, M, N, K, lda, ldb);
}

// paired variant: blockIdx.z selects pointer set (merges two equal-shape GEMMs)
struct GemmPair {
  const unsigned short *A0, *A1, *B0, *B1;
  const float *b0, *b1;
  void *C0, *C1;
};

template<int ACT, int OUTBF, int GX = 0>
__global__ __launch_bounds__(256) void k_gemm2z(
    GemmPair p, int M, int N, int K, int lda, int ldb)
{
  const int z = blockIdx.z;
  gemm2_body<ACT, OUTBF, GX>(z ? p.A1 : p.A0, z ? p.B1 : p.B0,
                             z ? p.b1 : p.b0, z ? p.C1 : p.C0,
                             M, N, K, lda, ldb);
}

// ---------------- fused out-projection GEMM: 512 thr, 128x256 tile ---------
// out[49152][768] = (relu(Ps[gather i0] + Pe[gather i1] + b1)) @ ow2^T + b2
// 8 waves (2 rows x 4 cols), acc[4][4]/wave (proven register profile).
// Per-thread A-prep halved (2 iters) and per-row-tile redundancy 6x -> 3x.
// XCD-colocated: the 3 n-blocks of a row-tile land on the same XCD.
__global__ __launch_bounds__(512, 4) void k_gout(
    const unsigned short* __restrict__ Ps, const unsigned short* __restrict__ Pe,
    const int* __restrict__ sidx, const float* __restrict__ b1,
    const unsigned short* __restrict__ Bw, const float* __restrict__ b2,
    float* __restrict__ out)
{
  __shared__ unsigned short Al[128 * 64];   // 16 KB
  __shared__ unsigned short Bl[256 * 64];   // 32 KB
  __shared__ int idx2[128][2];

  const int tid  = threadIdx.x;
  const int lane = tid & 63;
  const int wave = tid >> 6;        // 0..7
  const int wr = wave >> 2;         // 0..1 (row half)
  const int wc = wave & 3;          // 0..3 (col quarter)
  const int l16 = lane & 15, lq = lane >> 4;

  // 1152 blocks: xcd = wg&7; slot = wg>>3 (0..143); nblk = slot%3; tm = xcd + 8*(slot/3)
  const int wg   = blockIdx.x;
  const int xcd  = wg & 7;
  const int slot = wg >> 3;
  const int nblk = slot % 3;
  const int tm   = xcd + 8 * (slot / 3);   // 0..383
  const int b  = tm / 48;
  const int s0 = (tm % 48) * 128;
  const int n0 = nblk * 256;

  if (tid < 128){
    int s = s0 + tid;
    int i0 = sidx[((size_t)b * S_ + s) * 2 + 0];
    int i1 = sidx[((size_t)b * S_ + s) * 2 + 1];
    idx2[tid][0] = min(max(i0, 0), L_ - 1);
    idx2[tid][1] = min(max(i1, 0), L_ - 1);
  }
  __syncthreads();

  const int r_ = tid >> 3;            // 0..63
  const int p_ = tid & 7;
  const int cS = ((p_ ^ (r_ & 7)) * 8);
  const unsigned short* Bsrc[4];
  const unsigned short* As0[2];
  const unsigned short* As1[2];
  #pragma unroll
  for (int i = 0; i < 4; i++)
    Bsrc[i] = Bw + (size_t)(n0 + i * 64 + r_) * 3072 + cS;
  #pragma unroll
  for (int i = 0; i < 2; i++){
    int rr = i * 64 + r_;
    As0[i] = Ps + (size_t)(b * L_ + idx2[rr][0]) * 3072 + cS;
    As1[i] = Pe + (size_t)(b * L_ + idx2[rr][1]) * 3072 + cS;
  }

  f32x4 acc[4][4];
  #pragma unroll
  for (int a = 0; a < 4; a++)
    #pragma unroll
    for (int c = 0; c < 4; c++)
      acc[a][c] = (f32x4)0.f;

  const int sw0 = ((0 * 4 + lq) ^ (l16 & 7)) * 16;
  const int sw1 = ((1 * 4 + lq) ^ (l16 & 7)) * 16;
  const int aBase = (wr * 64 + l16) * 128;
  const int bBase = (wc * 64 + l16) * 128;

  for (int k0 = 0; k0 < 3072; k0 += 64){
    #pragma unroll
    for (int i = 0; i < 4; i++)
      gl_lds16(Bsrc[i] + k0, Bl + i * 4096 + tid * 8);
    float4 bb0 = *reinterpret_cast<const float4*>(b1 + k0 + cS);
    float4 bb1 = *reinterpret_cast<const float4*>(b1 + k0 + cS + 4);
    #pragma unroll
    for (int i = 0; i < 2; i++){
      uint4 va = *reinterpret_cast<const uint4*>(As0[i] + k0);
      uint4 ve = *reinterpret_cast<const uint4*>(As1[i] + k0);
      float f[8];
      f[0] = bflo(va.x) + bflo(ve.x) + bb0.x; f[1] = bfhi(va.x) + bfhi(ve.x) + bb0.y;
      f[2] = bflo(va.y) + bflo(ve.y) + bb0.z; f[3] = bfhi(va.y) + bfhi(ve.y) + bb0.w;
      f[4] = bflo(va.z) + bflo(ve.z) + bb1.x; f[5] = bfhi(va.z) + bfhi(ve.z) + bb1.y;
      f[6] = bflo(va.w) + bflo(ve.w) + bb1.z; f[7] = bfhi(va.w) + bfhi(ve.w) + bb1.w;
      unsigned short e[8];
      #pragma unroll
      for (int j = 0; j < 8; j++){ float v = f[j] > 0.f ? f[j] : 0.f; e[j] = f2bf(v); }
      uint4 rr;
      rr.x = (unsigned)e[0] | ((unsigned)e[1] << 16);
      rr.y = (unsigned)e[2] | ((unsigned)e[3] << 16);
      rr.z = (unsigned)e[4] | ((unsigned)e[5] << 16);
      rr.w = (unsigned)e[6] | ((unsigned)e[7] << 16);
      *reinterpret_cast<uint4*>(Al + i * 4096 + tid * 8) = rr;
    }
    __syncthreads();

    #pragma unroll
    for (int kk = 0; kk < 2; kk++){
      const int sw = kk ? sw1 : sw0;
      bf16x8 av[4], bv[4];
      #pragma unroll
      for (int mi = 0; mi < 4; mi++)
        av[mi] = *reinterpret_cast<const bf16x8*>((const char*)Al + aBase + mi * 2048 + sw);
      #pragma unroll
      for (int ni = 0; ni < 4; ni++)
        bv[ni] = *reinterpret_cast<const bf16x8*>((const char*)Bl + bBase + ni * 2048 + sw);
      #pragma unroll
      for (int mi = 0; mi < 4; mi++)
        #pragma unroll
        for (int ni = 0; ni < 4; ni++)
          acc[mi][ni] = __builtin_amdgcn_mfma_f32_16x16x32_bf16(av[mi], bv[ni], acc[mi][ni], 0, 0, 0);
    }
    __syncthreads();
  }

  #pragma unroll
  for (int mi = 0; mi < 4; mi++){
    #pragma unroll
    for (int r = 0; r < 4; r++){
      size_t row = (size_t)tm * 128 + wr * 64 + mi * 16 + lq * 4 + r;
      #pragma unroll
      for (int ni = 0; ni < 4; ni++){
        int col = n0 + wc * 64 + ni * 16 + l16;
        out[row * 768 + col] = acc[mi][ni][r] + b2[col];
      }
    }
  }
}

// ---------------- distributed LSTM v7 (round-8 winner; xg stride 3072) ------
static __device__ __forceinline__ unsigned long long ald8(const unsigned long long* p){
  return __hip_atomic_load(p, __ATOMIC_RELAXED, __HIP_MEMORY_SCOPE_AGENT);
}

__global__ __launch_bounds__(512, 2) void k_lstm7(
    const float* __restrict__ xgc,            // [4096][3072]: [fwd 1536 | bwd 1536]
    const unsigned short* __restrict__ Wbf,   // [2][1536][384] bf16
    const int* __restrict__ mask,
    unsigned short* __restrict__ hbf,         // [4096][768] bf16 out (masked)
    unsigned int* __restrict__ hg)            // [2][2][3072] tagged words (pre-zeroed)
{
  const int dir  = blockIdx.x / 6;
  const int part = blockIdx.x % 6;
  const int tid  = threadIdx.x;
  const int lane = tid & 63;
  const int w    = tid >> 6;            // wave 0..7
  const int l16  = lane & 15, lq = lane >> 4;

  __shared__ alignas(16) unsigned short hls[8 * HH];   // 6 KB, XOR-swizzled
  __shared__ float gsl[256 * 9];                        // padded gate staging

  const float* xg = xgc + dir * 1536;
  const unsigned short* Wg = Wbf + (size_t)dir * G4 * HH;
  unsigned int* hgd = hg + dir * 2 * (8 * HH);

  // resident W_hh B-frags: wave w covers local gate-rows w*32 .. w*32+31
  bf16x8 bfr0[12], bfr1[12];
  {
    int r0 = w * 32 + l16;
    int r1 = w * 32 + 16 + l16;
    int g0 = r0 >> 6, j0u = r0 & 63;
    int g1 = r1 >> 6, j1u = r1 & 63;
    const unsigned short* p0 = Wg + ((size_t)g0 * HH + part * 64 + j0u) * HH + lq * 8;
    const unsigned short* p1 = Wg + ((size_t)g1 * HH + part * 64 + j1u) * HH + lq * 8;
    #pragma unroll
    for (int kf = 0; kf < 12; kf++){
      bfr0[kf] = *reinterpret_cast<const bf16x8*>(p0 + kf * 32);
      bfr1[kf] = *reinterpret_cast<const bf16x8*>(p1 + kf * 32);
    }
  }

  if (tid < 384) reinterpret_cast<uint4*>(hls)[tid] = uint4{0,0,0,0};

  const int cb = tid >> 6;          // combine: batch = wave
  const int cj = tid & 63;          // combine: unit within part
  const int cu = part * 64 + cj;    // global unit
  float c_state = 0.f;

  const int w0  = tid * 6;
  const int rb  = w0 / HH;
  const int ru  = w0 % HH;

  // prefetch xg/mask for step 0
  float xi, xf, xgg, xo, mvf;
  {
    const int t0 = dir ? (L_ - 1) : 0;
    const float* xr = xg + ((size_t)cb * L_ + t0) * 3072;
    xi = xr[cu]; xf = xr[HH + cu]; xgg = xr[2 * HH + cu]; xo = xr[3 * HH + cu];
    mvf = (float)mask[cb * L_ + t0];
  }

  __syncthreads();

  for (int s = 0; s < L_; s++){
    const int t = dir ? (L_ - 1 - s) : s;

    // issue next step's xg loads (consumed next iteration -> full-step latency hiding)
    float nxi = 0.f, nxf = 0.f, nxg = 0.f, nxo = 0.f, nmv = 0.f;
    if (s + 1 < L_){
      const int tn = dir ? (L_ - 2 - s) : (s + 1);
      const float* xr = xg + ((size_t)cb * L_ + tn) * 3072;
      nxi = xr[cu]; nxf = xr[HH + cu]; nxg = xr[2 * HH + cu]; nxo = xr[3 * HH + cu];
      nmv = (float)mask[cb * L_ + tn];
    }

    if (s > 0){
      const unsigned long long tg = (unsigned long long)s;
      const unsigned long long* P =
        reinterpret_cast<const unsigned long long*>(hgd + ((s - 1) & 1) * (8 * HH) + w0);
      unsigned long long v0 = ald8(P), v1 = ald8(P + 1), v2 = ald8(P + 2);
      // combined retry: one round-trip refreshes all three words
      for (;;){
        bool ok0 = (((v0 >> 16) & 0xFFFFull) == tg) & ((v0 >> 48) == tg);
        bool ok1 = (((v1 >> 16) & 0xFFFFull) == tg) & ((v1 >> 48) == tg);
        bool ok2 = (((v2 >> 16) & 0xFFFFull) == tg) & ((v2 >> 48) == tg);
        if (ok0 & ok1 & ok2) break;
        v0 = ald8(P); v1 = ald8(P + 1); v2 = ald8(P + 2);
      }
      unsigned p01 = (unsigned)(v0 & 0xFFFFu) | ((unsigned)((v0 >> 32) & 0xFFFFu) << 16);
      unsigned p23 = (unsigned)(v1 & 0xFFFFu) | ((unsigned)((v1 >> 32) & 0xFFFFu) << 16);
      unsigned p45 = (unsigned)(v2 & 0xFFFFu) | ((unsigned)((v2 >> 32) & 0xFFFFu) << 16);
      *reinterpret_cast<unsigned*>((char*)hls + ((rb * 768 + (ru    ) * 2) ^ (rb << 4))) = p01;
      *reinterpret_cast<unsigned*>((char*)hls + ((rb * 768 + (ru + 2) * 2) ^ (rb << 4))) = p23;
      *reinterpret_cast<unsigned*>((char*)hls + ((rb * 768 + (ru + 4) * 2) ^ (rb << 4))) = p45;
    }
    __syncthreads();

    // gates = h @ Wslice^T : per wave 2 n-tiles x 12 k-frags
    f32x4 acc0 = (f32x4)0.f, acc1 = (f32x4)0.f;
    const int arow = l16 & 7;
    #pragma unroll
    for (int kf = 0; kf < 12; kf++){
      int by = (arow * 768 + kf * 64 + lq * 16) ^ (arow << 4);
      bf16x8 a = *reinterpret_cast<const bf16x8*>((const char*)hls + by);
      acc0 = __builtin_amdgcn_mfma_f32_16x16x32_bf16(a, bfr0[kf], acc0, 0, 0, 0);
      acc1 = __builtin_amdgcn_mfma_f32_16x16x32_bf16(a, bfr1[kf], acc1, 0, 0, 0);
    }
    if (lq < 2){
      int n0r = w * 32 + l16;
      int n1r = w * 32 + 16 + l16;
      #pragma unroll
      for (int r = 0; r < 4; r++){
        gsl[n0r * 9 + lq * 4 + r] = acc0[r];
        gsl[n1r * 9 + lq * 4 + r] = acc1[r];
      }
    }
    __syncthreads();

    // combine: thread = (batch cb, unit cj)
    {
      float gi = gsl[(0 * 64 + cj) * 9 + cb] + xi;
      float gf = gsl[(1 * 64 + cj) * 9 + cb] + xf;
      float gg = gsl[(2 * 64 + cj) * 9 + cb] + xgg;
      float go = gsl[(3 * 64 + cj) * 9 + cb] + xo;
      c_state = sigmoid_f(gf) * c_state + sigmoid_f(gi) * tanh_f(gg);
      float h = sigmoid_f(go) * tanh_f(c_state);
      unsigned short hb = f2bf(h);
      *reinterpret_cast<unsigned short*>((char*)hls + ((cb * 768 + cu * 2) ^ (cb << 4))) = hb;
      unsigned word = ((unsigned)(s + 1) << 16) | (unsigned)hb;
      __hip_atomic_store(&hgd[(s & 1) * (8 * HH) + cb * HH + cu], word,
                         __ATOMIC_RELAXED, __HIP_MEMORY_SCOPE_AGENT);
      hbf[((size_t)cb * L_ + t) * H_ + dir * HH + cu] = f2bf(h * mvf);
    }

    xi = nxi; xf = nxf; xgg = nxg; xo = nxo; mvf = nmv;
  }
}

extern "C" void kernel_launch(void* const* d_in, const int* in_sizes, int n_in,
                              void* d_out, int out_size, void* d_ws, size_t ws_size,
                              hipStream_t stream)
{
  (void)in_sizes; (void)n_in; (void)out_size; (void)ws_size;
  const float* we     = (const float*)d_in[0];
  const int*   mask   = (const int*)  d_in[1];
  const int*   sidx   = (const int*)  d_in[2];
  const float* pe     = (const float*)d_in[3];
  const float* w_ih_f = (const float*)d_in[4];
  const float* w_hh_f = (const float*)d_in[5];
  const float* b_ih_f = (const float*)d_in[6];
  const float* b_hh_f = (const float*)d_in[7];
  const float* w_ih_b = (const float*)d_in[8];
  const float* w_hh_b = (const float*)d_in[9];
  const float* b_ih_b = (const float*)d_in[10];
  const float* b_hh_b = (const float*)d_in[11];
  const float* sw1 = (const float*)d_in[12]; const float* sb1 = (const float*)d_in[13];
  const float* sw2 = (const float*)d_in[14]; const float* sb2 = (const float*)d_in[15];
  const float* ew1 = (const float*)d_in[16]; const float* eb1 = (const float*)d_in[17];
  const float* ew2 = (const float*)d_in[18]; const float* eb2 = (const float*)d_in[19];
  const float* ow1 = (const float*)d_in[20]; const float* ob1 = (const float*)d_in[21];
  const float* ow2 = (const float*)d_in[22]; const float* ob2 = (const float*)d_in[23];
  const float* pw1 = (const float*)d_in[24]; const float* pb1 = (const float*)d_in[25];
  const float* pw2 = (const float*)d_in[26]; const float* pb2 = (const float*)d_in[27];

  char* wsp = (char*)d_ws; size_t off = 0;
  auto alloc = [&](size_t bytes) -> void* {
    void* p = wsp + off;
    off += (bytes + 255) & ~(size_t)255;
    return p;
  };

  unsigned short* we_bf  = (unsigned short*)alloc((size_t)4096*768*2);
  unsigned short* wihc_bf= (unsigned short*)alloc((size_t)3072*768*2);   // [wihf;wihb]
  float* bcc   = (float*)alloc((size_t)3072*4);                          // [bc_f;bc_b]
  float* zerob = (float*)alloc((size_t)3072*4);
  float* sbe1  = (float*)alloc((size_t)6144*4);                          // [sb1;eb1]
  float* xgc   = (float*)alloc((size_t)4096*3072*4);   // reused later as Ps+Pe (bf16)
  unsigned short* whh_bf = (unsigned short*)alloc((size_t)2*1536*384*2);
  unsigned int* hg = (unsigned int*)alloc((size_t)2*2*8*384*4);
  unsigned short* h_bf  = (unsigned short*)alloc((size_t)4096*768*2);
  unsigned short* swe1b = (unsigned short*)alloc((size_t)6144*768*2);    // [sw1;ew1]
  unsigned short* sw2b  = (unsigned short*)alloc((size_t)768*3072*2);
  unsigned short* ew2b  = (unsigned short*)alloc((size_t)768*3072*2);
  unsigned short* ow1b  = (unsigned short*)alloc((size_t)3072*1536*2);
  unsigned short* ow2b  = (unsigned short*)alloc((size_t)768*3072*2);
  unsigned short* pw1b  = (unsigned short*)alloc((size_t)3072*768*2);
  unsigned short* pw2b  = (unsigned short*)alloc((size_t)768*3072*2);
  unsigned short* srep  = (unsigned short*)alloc((size_t)4096*768*2);
  unsigned short* erep  = (unsigned short*)alloc((size_t)4096*768*2);
  unsigned short* midc  = (unsigned short*)alloc((size_t)4096*6144*2);   // [mid_s|mid_e] cols
  unsigned short* pe_bf = (unsigned short*)alloc((size_t)200*768*2);
  unsigned short* pmid  = (unsigned short*)alloc((size_t)200*3072*2);

  unsigned short* Ps = (unsigned short*)xgc;                    // 4096*3072 bf16
  unsigned short* Pe = (unsigned short*)xgc + (size_t)4096*3072;

  hipMemsetAsync(hg, 0, (size_t)2*2*8*384*4, stream);
  hipMemsetAsync(zerob, 0, (size_t)3072*4, stream);
  hipMemcpyAsync(sbe1,        sb1, (size_t)3072*4, hipMemcpyDeviceToDevice, stream);
  hipMemcpyAsync(sbe1 + 3072, eb1, (size_t)3072*4, hipMemcpyDeviceToDevice, stream);

  // ---- all fp32->bf16 casts in one launch ----
  {
    CastArgs ca;
    const float* srcs[14] = { we, w_ih_f, w_ih_b, w_hh_f, w_hh_b, sw1, ew1,
                              sw2, ew2, ow1, ow2, pw1, pw2, pe };
    unsigned short* dsts[14] = { we_bf, wihc_bf, wihc_bf + 1536*768,
                                 whh_bf, whh_bf + 1536*384,
                                 swe1b, swe1b + 3072*768,
                                 sw2b, ew2b, ow1b, ow2b, pw1b, pw2b, pe_bf };
    long n4s[14] = { 4096L*768/4, 1536L*768/4, 1536L*768/4,
                     1536L*384/4, 1536L*384/4,
                     3072L*768/4, 3072L*768/4,
                     768L*3072/4, 768L*3072/4, 3072L*1536/4, 768L*3072/4,
                     3072L*768/4, 768L*3072/4, 200L*768/4 };
    long c = 0;
    for (int i = 0; i < 14; i++){ ca.s[i] = srcs[i]; ca.d[i] = dsts[i]; ca.cum[i] = c; c += n4s[i]; }
    ca.cum[14] = c;
    int grid = (int)((c + 255) / 256);
    k_cast_multi<<<grid, 256, 0, stream>>>(ca, c);
  }

  k_biascomb2<<<12, 256, 0, stream>>>(b_ih_f, b_hh_f, b_ih_b, b_hh_b, bcc);

  dim3 blk(256);
  // input-gate precompute, both directions in ONE GEMM (N=3072), fp32 out
  k_gemm2<0,0><<<dim3(24, 32), blk, 0, stream>>>(we_bf, wihc_bf, bcc, xgc, 4096, 3072, 768, 768, 768);

  k_lstm7<<<12, 512, 0, stream>>>(xgc, whh_bf, mask, h_bf, hg);

  // start+end first-layer MLP in ONE GEMM (N=6144) -> midc [4096][6144]
  k_gemm2<1,1><<<dim3(48, 32), blk, 0, stream>>>(h_bf, swe1b, sbe1, midc, 4096, 6144, 768, 768, 768);

  // second layers merged (z=2); GX=1 -> same-A blocks same XCD
  {
    GemmPair p;
    p.A0 = midc;        p.B0 = sw2b; p.b0 = sb2; p.C0 = srep;
    p.A1 = midc + 3072; p.B1 = ew2b; p.b1 = eb2; p.C1 = erep;
    k_gemm2z<1,1,1><<<dim3(32, 6, 2), blk, 0, stream>>>(p, 4096, 768, 3072, 6144, 3072);
  }

  // P_s = relu(srep) @ Ws^T ; P_e = relu(erep) @ We^T merged (ow1 halves)
  {
    GemmPair p;
    p.A0 = srep; p.B0 = ow1b;       p.b0 = zerob; p.C0 = Ps;
    p.A1 = erep; p.B1 = ow1b + 768; p.b1 = zerob; p.C1 = Pe;
    k_gemm2z<0,1,0><<<dim3(24, 32, 2), blk, 0, stream>>>(p, 4096, 3072, 768, 768, 1536);
  }

  float* outp = (float*)d_out;
  // fused gather + add + bias + relu + out-projection (512 thr, 128x256 tile)
  k_gout<<<1152, dim3(512), 0, stream>>>(Ps, Pe, sidx, ob1, ow2b, ob2, outp);

  // prompt projection
  k_gemm2<1,1><<<dim3(24, 2), blk, 0, stream>>>(pe_bf, pw1b, pb1, pmid, 200, 3072, 768, 768, 768);
  k_gemm2<0,0><<<dim3( 6, 2), blk, 0, stream>>>(pmid, pw2b, pb2,
                                                outp + (size_t)37748736, 200, 768, 3072, 3072, 3072);
}